// Round 3
// baseline (855.512 us; speedup 1.0000x reference)
//
#include <hip/hip_runtime.h>
#include <hip/hip_bf16.h>
#include <math.h>

// ---------- types & helpers ----------
typedef __bf16 bf16x8 __attribute__((ext_vector_type(8)));
typedef float f32x4 __attribute__((ext_vector_type(4)));

#define DEV static __device__ __forceinline__

DEV unsigned short f2b(float f){
  unsigned int u = __float_as_uint(f);
  u += 0x7fffu + ((u>>16)&1u);
  return (unsigned short)(u>>16);
}
DEV float b2f(unsigned short h){ return __uint_as_float(((unsigned int)h)<<16); }
DEV unsigned int pck(float a, float b){
  return (unsigned int)f2b(a) | ((unsigned int)f2b(b)<<16);
}
DEV f32x4 mfma16(bf16x8 a, bf16x8 b, f32x4 c){
  return __builtin_amdgcn_mfma_f32_16x16x32_bf16(a,b,c,0,0,0);
}
DEV float sigm(float x){ return 1.f/(1.f+expf(-x)); }
// lane must be a compile-time constant after unrolling -> v_readlane_b32 (VALU, not LDS)
#define RDLANE(v, l) __uint_as_float(__builtin_amdgcn_readlane(__float_as_uint(v), (l)))

// ---------- I0: slots init ----------
__global__ __launch_bounds__(256) void k_slots_init(
    const float* __restrict__ noise, const float* __restrict__ mu,
    const float* __restrict__ ls, float* __restrict__ sf,
    unsigned short* __restrict__ sb){
  int i = blockIdx.x*256 + threadIdx.x;   // 131072 total
  int d = i & 255;
  float val = mu[d] + expf(ls[d]) * noise[i];
  sf[i] = val; sb[i] = f2b(val);
}

// ---------- prep: bf16 copies of W_hh, W1, W2 ----------
__global__ __launch_bounds__(256) void k_prep_b16(
    const float* __restrict__ Whh, const float* __restrict__ W1,
    const float* __restrict__ W2,
    unsigned short* __restrict__ Whhb, unsigned short* __restrict__ W1b,
    unsigned short* __restrict__ W2b){
  int i = blockIdx.x*256 + threadIdx.x;
  if (i < 196608) Whhb[i] = f2b(Whh[i]);
  else if (i < 327680) W1b[i-196608] = f2b(W1[i-196608]);
  else if (i < 458752) W2b[i-327680] = f2b(W2[i-327680]);
}

// ---------- P1 ----------
__global__ __launch_bounds__(256) void k_pre1(
    const float* __restrict__ Wq, const float* __restrict__ Wk,
    const float* __restrict__ bq, const float* __restrict__ bk,
    unsigned short* __restrict__ WcT, float* __restrict__ bc,
    float* __restrict__ wqbk, float* __restrict__ cbk){
  int c = blockIdx.x, d = threadIdx.x;
  float acc = 0.f;
  for (int e=0;e<256;e++)
    acc += Wq[e*256+d] * Wk[e*256+c];
  WcT[c*256+d] = f2b(acc);
  __shared__ float red[256];
  red[d] = bq[d] * Wk[d*256+c];
  __syncthreads();
  for (int s2=128;s2>0;s2>>=1){ if (d<s2) red[d]+=red[d+s2]; __syncthreads(); }
  if (d==0) bc[c] = red[0];
  if (blockIdx.x==0){
    float a2=0.f;
    for (int e=0;e<256;e++) a2 += Wq[e*256+d]*bk[e];
    wqbk[d] = a2;
    __syncthreads();
    red[d] = bq[d]*bk[d];
    __syncthreads();
    for (int s2=128;s2>0;s2>>=1){ if (d<s2) red[d]+=red[d+s2]; __syncthreads(); }
    if (d==0) cbk[0] = red[0];
  }
}

// ---------- P2 ----------
__global__ __launch_bounds__(256) void k_pre2(
    const float* __restrict__ W_ih, const float* __restrict__ Wv,
    const float* __restrict__ bv, const float* __restrict__ b_ih,
    unsigned short* __restrict__ WvihT, float* __restrict__ bvih){
  int j = blockIdx.x, c = threadIdx.x;
  float acc=0.f;
  for (int d=0; d<256; d++)
    acc += W_ih[j*256+d] * Wv[d*256+c];
  WvihT[j*256+c] = f2b(acc);
  __shared__ float red[256];
  red[c] = bv[c] * W_ih[j*256+c];
  __syncthreads();
  for (int s2=128;s2>0;s2>>=1){ if (c<s2) red[c]+=red[c+s2]; __syncthreads(); }
  if (c==0) bvih[j] = red[0] + b_ih[j];
}

// ---------- I1: sn=LN(slots); q' = sn@Wc + bc; dotbias; zero attn_sum ----------
__global__ __launch_bounds__(256) void k_slot_q(
    const float* __restrict__ sf, const float* __restrict__ g,
    const float* __restrict__ be,
    const unsigned short* __restrict__ WcT, const float* __restrict__ bc,
    const float* __restrict__ wqbk, const float* __restrict__ cbk,
    unsigned short* __restrict__ qp, float* __restrict__ dotbias,
    float* __restrict__ attn_sum){
  __shared__ __align__(16) unsigned short sn[16][264];
  int b = blockIdx.x, t = threadIdx.x;
  if (t < 8) attn_sum[b*8+t] = 0.f;
  if (t < 8) dotbias[b*16+8+t] = 0.f;
  int r = t>>5, j = t&31;
  const float* pr = sf + (b*8+r)*256 + j*8;
  float v[8]; float s=0.f;
  #pragma unroll
  for (int i=0;i<8;i++){ v[i]=pr[i]; s+=v[i]; }
  s += __shfl_xor(s,1); s+=__shfl_xor(s,2); s+=__shfl_xor(s,4);
  s += __shfl_xor(s,8); s+=__shfl_xor(s,16);
  float m = s*(1.f/256.f);
  float vs=0.f;
  #pragma unroll
  for (int i=0;i<8;i++){ float d = v[i]-m; vs += d*d; }
  vs += __shfl_xor(vs,1); vs+=__shfl_xor(vs,2); vs+=__shfl_xor(vs,4);
  vs += __shfl_xor(vs,8); vs+=__shfl_xor(vs,16);
  float rstd = rsqrtf(vs*(1.f/256.f) + 1e-5f);
  float dp = 0.f;
  #pragma unroll
  for (int i=0;i<8;i++){
    int d = j*8+i;
    float snv = (v[i]-m)*rstd*g[d] + be[d];
    sn[r][d] = f2b(snv);
    dp += snv * wqbk[d];
  }
  dp += __shfl_xor(dp,1); dp+=__shfl_xor(dp,2); dp+=__shfl_xor(dp,4);
  dp += __shfl_xor(dp,8); dp+=__shfl_xor(dp,16);
  if (j==0) dotbias[b*16+r] = dp + cbk[0];
  for (int rr=8; rr<16; ++rr){ sn[rr][t]=0; if (t<8) sn[rr][256+t]=0; }
  __syncthreads();
  int lane = t&63, wv = t>>6, l16 = lane&15, quad = lane>>4;
  #pragma unroll
  for (int nt=0; nt<4; ++nt){
    int col = (wv*4+nt)*16 + l16;
    f32x4 acc = {0.f,0.f,0.f,0.f};
    #pragma unroll
    for (int kk=0;kk<8;kk++){
      int kd = kk*32 + quad*8;
      bf16x8 a = *(const bf16x8*)&sn[l16][kd];
      bf16x8 bb = *(const bf16x8*)(WcT + col*256 + kd);
      acc = mfma16(a,bb,acc);
    }
    float bcv = bc[col];
    #pragma unroll
    for (int ri=0;ri<4;ri++){
      int rw = quad*4+ri;
      qp[(b*16+rw)*256 + col] = f2b(acc[ri] + bcv);
    }
  }
}

// ---------- I2a (iteration 0): fused LN + dots + softmax + partial u ----------
// grid = 64 batches x 16 chunks = 1024 blocks, 4 tiles of 64 tokens each.
// Stage 3 is wave-local: each wave owns its 16 n's; attn distributed via
// v_readlane (VALU) instead of LDS broadcasts; per-wave partial u reduced
// through recycled xt space at the end.
__global__ __launch_bounds__(256) void k_iter0(
    const float* __restrict__ in, const float* __restrict__ g,
    const float* __restrict__ be, const unsigned short* __restrict__ qp,
    const float* __restrict__ dotbias, float* __restrict__ attn_sum,
    float* __restrict__ upart, unsigned short* __restrict__ xc_w){
  __shared__ __align__(16) unsigned short xt[64][264];
  int t = threadIdx.x;
  int b = blockIdx.x >> 4, sp = blockIdx.x & 15;
  int lane=t&63, wv=t>>6, l16=lane&15, quad=lane>>4;
  bf16x8 aq[8];
  #pragma unroll
  for (int kk=0;kk<8;kk++)
    aq[kk] = *(const bf16x8*)(qp + ((size_t)(b*16+l16))*256 + kk*32+quad*8);
  float db[4];
  #pragma unroll
  for (int ri=0;ri<4;ri++) db[ri] = dotbias[b*16 + quad*4 + ri];
  float acc[8][4];
  #pragma unroll
  for (int k2=0;k2<8;k2++){ acc[k2][0]=0;acc[k2][1]=0;acc[k2][2]=0;acc[k2][3]=0; }
  float rbs[4] = {0.f,0.f,0.f,0.f};
  int rl = t>>3, j = t&7;
  for (int tile=0; tile<4; ++tile){
    int n0 = sp*256 + tile*64;
    __syncthreads();   // xt free from previous tile's readers
    // --- stage 1: LN(inputs) -> LDS bf16 + global bf16 cache ---
    #pragma unroll
    for (int p=0;p<2;p++){
      int row = p*32 + rl;
      const float* pr = in + ((size_t)(b*4096 + n0 + row))*256 + j*32;
      float v[32]; float s=0.f;
      #pragma unroll
      for (int c=0;c<8;c++) *(float4*)(v+c*4) = *(const float4*)(pr + c*4);
      #pragma unroll
      for (int i=0;i<32;i++) s += v[i];
      s += __shfl_xor(s,1); s+=__shfl_xor(s,2); s+=__shfl_xor(s,4);
      float m = s*(1.f/256.f);
      float vs=0.f;
      #pragma unroll
      for (int i=0;i<32;i++){ float d=v[i]-m; vs+=d*d; }
      vs+=__shfl_xor(vs,1); vs+=__shfl_xor(vs,2); vs+=__shfl_xor(vs,4);
      float rstd = rsqrtf(vs*(1.f/256.f)+1e-5f);
      #pragma unroll
      for (int c=0;c<4;c++){
        float o[8];
        #pragma unroll
        for (int q=0;q<8;q++){
          int d = j*32 + c*8 + q;
          o[q] = (v[c*8+q]-m)*rstd*g[d] + be[d];
        }
        uint4 w4;
        w4.x=pck(o[0],o[1]); w4.y=pck(o[2],o[3]);
        w4.z=pck(o[4],o[5]); w4.w=pck(o[6],o[7]);
        *(uint4*)&xt[row][j*32 + c*8] = w4;
        *(uint4*)(xc_w + ((size_t)(b*4096 + n0 + row))*256 + j*32 + c*8) = w4;
      }
    }
    __syncthreads();
    // --- stage 2: dots + softmax over slots (wave-local rows) ---
    f32x4 dacc = {0.f,0.f,0.f,0.f};
    #pragma unroll
    for (int kk=0;kk<8;kk++){
      int kd = kk*32 + quad*8;
      bf16x8 bb = *(const bf16x8*)&xt[wv*16 + l16][kd];
      dacc = mfma16(aq[kk],bb,dacc);
    }
    const float scale = 0.0625f;
    float val[4];
    #pragma unroll
    for (int ri=0;ri<4;ri++) val[ri] = (dacc[ri] + db[ri]) * scale;
    float mx = fmaxf(fmaxf(val[0],val[1]), fmaxf(val[2],val[3]));
    mx = fmaxf(mx, __shfl_xor(mx,16));
    float e[4], s4=0.f;
    #pragma unroll
    for (int ri=0;ri<4;ri++){ e[ri] = expf(val[ri]-mx); s4 += e[ri]; }
    float s8 = s4 + __shfl_xor(s4,16);
    float inv = 1.f/s8;
    float av[4];
    #pragma unroll
    for (int ri=0;ri<4;ri++) av[ri] = e[ri]*inv;
    if (quad < 2){
      #pragma unroll
      for (int ri=0;ri<4;ri++){
        float ss = av[ri];
        ss += __shfl_xor(ss,1); ss+=__shfl_xor(ss,2);
        ss += __shfl_xor(ss,4); ss+=__shfl_xor(ss,8);
        if (l16==0) rbs[ri] += ss;
      }
    }
    // --- stage 3: wave-local n-slice; attn via readlane (VALU) ---
    #pragma unroll
    for (int nl=0; nl<16; ++nl){
      int n = wv*16 + nl;
      float xv0 = b2f(xt[n][lane]);
      float xv1 = b2f(xt[n][64+lane]);
      float xv2 = b2f(xt[n][128+lane]);
      float xv3 = b2f(xt[n][192+lane]);
      #pragma unroll
      for (int ri=0;ri<4;ri++){
        float alo = RDLANE(av[ri], nl);
        float ahi = RDLANE(av[ri], nl+16);
        acc[ri][0]   += alo*xv0; acc[ri][1]   += alo*xv1;
        acc[ri][2]   += alo*xv2; acc[ri][3]   += alo*xv3;
        acc[4+ri][0] += ahi*xv0; acc[4+ri][1] += ahi*xv1;
        acc[4+ri][2] += ahi*xv2; acc[4+ri][3] += ahi*xv3;
      }
    }
  }
  // --- block reduce of per-wave partials through recycled xt ---
  __syncthreads();
  float* ured = (float*)&xt[0][0];   // 32 KB
  #pragma unroll
  for (int k2=0;k2<8;k2++)
    #pragma unroll
    for (int cc=0;cc<4;cc++)
      ured[(wv*8+k2)*256 + cc*64 + lane] = acc[k2][cc];
  __syncthreads();
  float* o = upart + (size_t)sp*131072 + ((size_t)b*8)*256 + t;
  #pragma unroll
  for (int k2=0;k2<8;k2++){
    float s = ured[k2*256+t] + ured[(8+k2)*256+t]
            + ured[(16+k2)*256+t] + ured[(24+k2)*256+t];
    o[(size_t)k2*256] = s;
  }
  if (quad < 2 && l16 == 0){
    #pragma unroll
    for (int ri=0;ri<4;ri++)
      atomicAdd(&attn_sum[b*8 + quad*4 + ri], rbs[ri]);
  }
}

// ---------- I2b (iterations 1,2): bf16 cache, register-prefetched ----------
__global__ __launch_bounds__(256) void k_iter(
    const unsigned short* __restrict__ xc,
    const unsigned short* __restrict__ qp,
    const float* __restrict__ dotbias, float* __restrict__ attn_sum,
    float* __restrict__ upart, float* __restrict__ attn_out){
  __shared__ __align__(16) unsigned short xt[64][264];
  int t = threadIdx.x;
  int b = blockIdx.x >> 4, sp = blockIdx.x & 15;
  int lane=t&63, wv=t>>6, l16=lane&15, quad=lane>>4;
  bf16x8 aq[8];
  #pragma unroll
  for (int kk=0;kk<8;kk++)
    aq[kk] = *(const bf16x8*)(qp + ((size_t)(b*16+l16))*256 + kk*32+quad*8);
  float db[4];
  #pragma unroll
  for (int ri=0;ri<4;ri++) db[ri] = dotbias[b*16 + quad*4 + ri];
  float acc[8][4];
  #pragma unroll
  for (int k2=0;k2<8;k2++){ acc[k2][0]=0;acc[k2][1]=0;acc[k2][2]=0;acc[k2][3]=0; }
  float rbs[4] = {0.f,0.f,0.f,0.f};
  int rl = t>>3, j = t&7;
  const unsigned short* cbase = xc + ((size_t)(b*4096 + sp*256))*256;
  uint4 R[8];
  #pragma unroll
  for (int p=0;p<2;p++){
    const unsigned short* pr = cbase + (size_t)(p*32+rl)*256 + j*32;
    #pragma unroll
    for (int c=0;c<4;c++) R[p*4+c] = *(const uint4*)(pr + c*8);
  }
  for (int tile=0; tile<4; ++tile){
    // --- stage 1: dump prefetched registers into LDS ---
    #pragma unroll
    for (int p=0;p<2;p++){
      #pragma unroll
      for (int c=0;c<4;c++)
        *(uint4*)&xt[p*32+rl][j*32 + c*8] = R[p*4+c];
    }
    __syncthreads();
    if (tile<3){
      const unsigned short* nb = cbase + (size_t)(tile+1)*64*256;
      #pragma unroll
      for (int p=0;p<2;p++){
        const unsigned short* pr = nb + (size_t)(p*32+rl)*256 + j*32;
        #pragma unroll
        for (int c=0;c<4;c++) R[p*4+c] = *(const uint4*)(pr + c*8);
      }
    }
    int n0 = sp*256 + tile*64;
    // --- stage 2: dots + softmax (wave-local rows) ---
    f32x4 dacc = {0.f,0.f,0.f,0.f};
    #pragma unroll
    for (int kk=0;kk<8;kk++){
      int kd = kk*32 + quad*8;
      bf16x8 bb = *(const bf16x8*)&xt[wv*16 + l16][kd];
      dacc = mfma16(aq[kk],bb,dacc);
    }
    const float scale = 0.0625f;
    float val[4];
    #pragma unroll
    for (int ri=0;ri<4;ri++) val[ri] = (dacc[ri] + db[ri]) * scale;
    float mx = fmaxf(fmaxf(val[0],val[1]), fmaxf(val[2],val[3]));
    mx = fmaxf(mx, __shfl_xor(mx,16));
    float e[4], s4=0.f;
    #pragma unroll
    for (int ri=0;ri<4;ri++){ e[ri] = expf(val[ri]-mx); s4 += e[ri]; }
    float s8 = s4 + __shfl_xor(s4,16);
    float inv = 1.f/s8;
    float av[4];
    #pragma unroll
    for (int ri=0;ri<4;ri++) av[ri] = e[ri]*inv;
    if (quad < 2){
      int nl = wv*16 + l16;
      #pragma unroll
      for (int ri=0;ri<4;ri++){
        int kr = quad*4+ri;
        if (attn_out)
          attn_out[((size_t)(b*8+kr))*4096 + n0 + nl] = av[ri];
        float ss = av[ri];
        ss += __shfl_xor(ss,1); ss+=__shfl_xor(ss,2);
        ss += __shfl_xor(ss,4); ss+=__shfl_xor(ss,8);
        if (l16==0) rbs[ri] += ss;
      }
    }
    // --- stage 3: wave-local n-slice; attn via readlane (VALU) ---
    #pragma unroll
    for (int nl=0; nl<16; ++nl){
      int n = wv*16 + nl;
      float xv0 = b2f(xt[n][lane]);
      float xv1 = b2f(xt[n][64+lane]);
      float xv2 = b2f(xt[n][128+lane]);
      float xv3 = b2f(xt[n][192+lane]);
      #pragma unroll
      for (int ri=0;ri<4;ri++){
        float alo = RDLANE(av[ri], nl);
        float ahi = RDLANE(av[ri], nl+16);
        acc[ri][0]   += alo*xv0; acc[ri][1]   += alo*xv1;
        acc[ri][2]   += alo*xv2; acc[ri][3]   += alo*xv3;
        acc[4+ri][0] += ahi*xv0; acc[4+ri][1] += ahi*xv1;
        acc[4+ri][2] += ahi*xv2; acc[4+ri][3] += ahi*xv3;
      }
    }
    __syncthreads();   // xt consumed; safe to overwrite next tile
  }
  // --- block reduce of per-wave partials through recycled xt ---
  float* ured = (float*)&xt[0][0];
  #pragma unroll
  for (int k2=0;k2<8;k2++)
    #pragma unroll
    for (int cc=0;cc<4;cc++)
      ured[(wv*8+k2)*256 + cc*64 + lane] = acc[k2][cc];
  __syncthreads();
  float* o = upart + (size_t)sp*131072 + ((size_t)b*8)*256 + t;
  #pragma unroll
  for (int k2=0;k2<8;k2++){
    float s = ured[k2*256+t] + ured[(8+k2)*256+t]
            + ured[(16+k2)*256+t] + ured[(24+k2)*256+t];
    o[(size_t)k2*256] = s;
  }
  if (quad < 2 && l16 == 0){
    #pragma unroll
    for (int ri=0;ri<4;ri++)
      atomicAdd(&attn_sum[b*8 + quad*4 + ri], rbs[ri]);
  }
}

// ---------- I3 fused slot chain (unchanged from round 2) ----------
__global__ __launch_bounds__(512) void k_step(
    const float* __restrict__ upart, float* __restrict__ asum,
    float* __restrict__ sf, unsigned short* __restrict__ sb,
    const unsigned short* __restrict__ WvihT, const float* __restrict__ bvih,
    const unsigned short* __restrict__ Whhb, const float* __restrict__ bhh,
    const float* __restrict__ lnffg, const float* __restrict__ lnffb,
    const unsigned short* __restrict__ W1b, const float* __restrict__ b1,
    const unsigned short* __restrict__ W2b, const float* __restrict__ b2v,
    const float* __restrict__ lnsg, const float* __restrict__ lnsb,
    const unsigned short* __restrict__ WcT, const float* __restrict__ bc,
    const float* __restrict__ wqbk, const float* __restrict__ cbk,
    unsigned short* __restrict__ qp, float* __restrict__ dotb,
    float* __restrict__ out_slots, int last){
  __shared__ __align__(16) unsigned short ub16[16][264];
  __shared__ __align__(16) float hls[16][268];
  __shared__ __align__(16) unsigned short sn[16][264];
  __shared__ __align__(16) unsigned short s1t[16][520];
  __shared__ float redh[8][16], redq[8][16], mr[16], rs[16];
  int t = threadIdx.x;
  int Bk = blockIdx.x;                 // batches 2*Bk, 2*Bk+1
  int bb0 = Bk*2;
  int lane=t&63, wv=t>>6, l16=lane&15, quad=lane>>4;
  {
    int r16 = t>>5, c0 = (t&31)*8;
    size_t base = ((size_t)(Bk*16 + r16))*256 + c0;
    float4 a0={0,0,0,0}, a1={0,0,0,0};
    #pragma unroll
    for (int sp2=0; sp2<16; ++sp2){
      const float* p = upart + (size_t)sp2*131072 + base;
      float4 u0=*(const float4*)(p+0), u1=*(const float4*)(p+4);
      a0.x+=u0.x;a0.y+=u0.y;a0.z+=u0.z;a0.w+=u0.w;
      a1.x+=u1.x;a1.y+=u1.y;a1.z+=u1.z;a1.w+=u1.w;
    }
    float inv = 1.f/(asum[Bk*16 + r16] + 1e-8f);
    float uu[8] = {a0.x,a0.y,a0.z,a0.w,a1.x,a1.y,a1.z,a1.w};
    #pragma unroll
    for (int c=0;c<8;c+=2)
      *(unsigned int*)&ub16[r16][c0+c] = pck(uu[c]*inv, uu[c+1]*inv);
  }
  __syncthreads();
  if (t < 16) asum[Bk*16 + t] = 0.f;
  bf16x8 afi[8], afh[8];
  #pragma unroll
  for (int kk=0;kk<8;kk++){
    int kd = kk*32+quad*8;
    afi[kk] = *(const bf16x8*)&ub16[l16][kd];
    afh[kk] = *(const bf16x8*)(sb + ((size_t)(Bk*16+l16))*256 + kd);
  }
  float sh[4]={0,0,0,0}, sq[4]={0,0,0,0};
  #pragma unroll
  for (int jj=0;jj<2;jj++){
    int jt = wv*2 + jj;
    int dR = jt*16 + l16;
    f32x4 cIR={0,0,0,0}, cIZ={0,0,0,0}, cIN={0,0,0,0};
    f32x4 cHR={0,0,0,0}, cHZ={0,0,0,0}, cHN={0,0,0,0};
    #pragma unroll
    for (int kk=0;kk<8;kk++){
      int kd = kk*32+quad*8;
      cIR = mfma16(afi[kk], *(const bf16x8*)(WvihT + (size_t)dR*256 + kd), cIR);
      cIZ = mfma16(afi[kk], *(const bf16x8*)(WvihT + (size_t)(256+dR)*256 + kd), cIZ);
      cIN = mfma16(afi[kk], *(const bf16x8*)(WvihT + (size_t)(512+dR)*256 + kd), cIN);
      cHR = mfma16(afh[kk], *(const bf16x8*)(Whhb + (size_t)dR*256 + kd), cHR);
      cHZ = mfma16(afh[kk], *(const bf16x8*)(Whhb + (size_t)(256+dR)*256 + kd), cHZ);
      cHN = mfma16(afh[kk], *(const bf16x8*)(Whhb + (size_t)(512+dR)*256 + kd), cHN);
    }
    float biR = bvih[dR], biZ = bvih[256+dR], biN = bvih[512+dR];
    float bhR = bhh[dR], bhZ = bhh[256+dR], bhN = bhh[512+dR];
    #pragma unroll
    for (int ri=0;ri<4;ri++){
      int row = quad*4+ri;
      float hp = sf[((size_t)(Bk*16+row))*256 + dR];
      float rg = sigm(cIR[ri]+biR + cHR[ri]+bhR);
      float z  = sigm(cIZ[ri]+biZ + cHZ[ri]+bhZ);
      float nn = tanhf(cIN[ri]+biN + rg*(cHN[ri]+bhN));
      float h = (1.f-z)*nn + z*hp;
      hls[row][dR] = h;
      sh[ri] += h; sq[ri] += h*h;
    }
  }
  #pragma unroll
  for (int ri=0;ri<4;ri++){
    sh[ri]+=__shfl_xor(sh[ri],1); sh[ri]+=__shfl_xor(sh[ri],2);
    sh[ri]+=__shfl_xor(sh[ri],4); sh[ri]+=__shfl_xor(sh[ri],8);
    sq[ri]+=__shfl_xor(sq[ri],1); sq[ri]+=__shfl_xor(sq[ri],2);
    sq[ri]+=__shfl_xor(sq[ri],4); sq[ri]+=__shfl_xor(sq[ri],8);
  }
  if (l16==0){
    #pragma unroll
    for (int ri=0;ri<4;ri++){
      redh[wv][quad*4+ri] = sh[ri];
      redq[wv][quad*4+ri] = sq[ri];
    }
  }
  __syncthreads();
  if (t < 16){
    float s = redh[0][t]+redh[1][t]+redh[2][t]+redh[3][t]
            + redh[4][t]+redh[5][t]+redh[6][t]+redh[7][t];
    float q = redq[0][t]+redq[1][t]+redq[2][t]+redq[3][t]
            + redq[4][t]+redq[5][t]+redq[6][t]+redq[7][t];
    float m = s*(1.f/256.f);
    float var = q*(1.f/256.f) - m*m;
    mr[t] = m; rs[t] = rsqrtf(var + 1e-5f);
  }
  __syncthreads();
  {
    int row = t>>5, c0 = (t&31)*8;
    float m = mr[row], rstd = rs[row];
    #pragma unroll
    for (int c=0;c<8;c+=2){
      int d = c0+c;
      float o0 = (hls[row][d]-m)*rstd*lnffg[d] + lnffb[d];
      float o1 = (hls[row][d+1]-m)*rstd*lnffg[d+1] + lnffb[d+1];
      *(unsigned int*)&sn[row][d] = pck(o0,o1);
    }
  }
  __syncthreads();
  {
    bf16x8 af[8];
    #pragma unroll
    for (int kk=0;kk<8;kk++)
      af[kk] = *(const bf16x8*)&sn[l16][kk*32+quad*8];
    #pragma unroll
    for (int ct=wv*4; ct<wv*4+4; ++ct){
      int col = ct*16+l16;
      f32x4 acc={0,0,0,0};
      #pragma unroll
      for (int kk=0;kk<8;kk++)
        acc = mfma16(af[kk], *(const bf16x8*)(W1b + (size_t)col*256 + kk*32+quad*8), acc);
      float bb = b1[col];
      #pragma unroll
      for (int ri=0;ri<4;ri++){
        float v2 = acc[ri]+bb; v2 = v2>0.f? v2:0.f;
        s1t[quad*4+ri][col] = f2b(v2);
      }
    }
  }
  __syncthreads();
  {
    bf16x8 af[16];
    #pragma unroll
    for (int kk=0;kk<16;kk++)
      af[kk] = *(const bf16x8*)&s1t[l16][kk*32+quad*8];
    #pragma unroll
    for (int ct=wv*2; ct<wv*2+2; ++ct){
      int col = ct*16+l16;
      f32x4 acc={0,0,0,0};
      #pragma unroll
      for (int kk=0;kk<16;kk++)
        acc = mfma16(af[kk], *(const bf16x8*)(W2b + (size_t)col*512 + kk*32+quad*8), acc);
      float bb = b2v[col];
      #pragma unroll
      for (int ri=0;ri<4;ri++){
        int row = quad*4+ri;
        float v2 = acc[ri] + bb + hls[row][col];
        size_t gidx = ((size_t)(Bk*16+row))*256 + col;
        sf[gidx] = v2;
        sb[gidx] = f2b(v2);
        if (last) out_slots[gidx] = v2;
        hls[row][col] = v2;
      }
    }
  }
  if (!last){
    __syncthreads();
    {
      int row = t>>5, c0 = (t&31)*8;
      float ps=0.f, pq=0.f;
      float hv[8];
      #pragma unroll
      for (int c=0;c<8;c++){ hv[c]=hls[row][c0+c]; ps+=hv[c]; pq+=hv[c]*hv[c]; }
      ps+=__shfl_xor(ps,1); ps+=__shfl_xor(ps,2); ps+=__shfl_xor(ps,4);
      ps+=__shfl_xor(ps,8); ps+=__shfl_xor(ps,16);
      pq+=__shfl_xor(pq,1); pq+=__shfl_xor(pq,2); pq+=__shfl_xor(pq,4);
      pq+=__shfl_xor(pq,8); pq+=__shfl_xor(pq,16);
      float m = ps*(1.f/256.f);
      float var = pq*(1.f/256.f) - m*m;
      float rstd = rsqrtf(var + 1e-5f);
      float dp = 0.f;
      #pragma unroll
      for (int c=0;c<8;c+=2){
        int d = c0+c;
        float o0 = (hv[c]-m)*rstd*lnsg[d] + lnsb[d];
        float o1 = (hv[c+1]-m)*rstd*lnsg[d+1] + lnsb[d+1];
        dp += o0*wqbk[d] + o1*wqbk[d+1];
        *(unsigned int*)&sn[row][d] = pck(o0,o1);
      }
      dp+=__shfl_xor(dp,1); dp+=__shfl_xor(dp,2); dp+=__shfl_xor(dp,4);
      dp+=__shfl_xor(dp,8); dp+=__shfl_xor(dp,16);
      if ((t&31)==0){
        int bloc = row>>3, rr = row&7;
        dotb[(bb0+bloc)*16 + rr] = dp + cbk[0];
      }
    }
    __syncthreads();
    {
      bf16x8 af[8];
      #pragma unroll
      for (int kk=0;kk<8;kk++)
        af[kk] = *(const bf16x8*)&sn[l16][kk*32+quad*8];
      #pragma unroll
      for (int ct=wv*2; ct<wv*2+2; ++ct){
        int col = ct*16+l16;
        f32x4 acc={0,0,0,0};
        #pragma unroll
        for (int kk=0;kk<8;kk++)
          acc = mfma16(af[kk], *(const bf16x8*)(WcT + (size_t)col*256 + kk*32+quad*8), acc);
        float bcv = bc[col];
        #pragma unroll
        for (int ri=0;ri<4;ri++){
          int row = quad*4+ri;
          int bloc = row>>3, rr = row&7;
          qp[((size_t)((bb0+bloc)*16 + rr))*256 + col] = f2b(acc[ri] + bcv);
        }
      }
    }
  }
}

// ---------- launch ----------
extern "C" void kernel_launch(void* const* d_in, const int* in_sizes, int n_in,
                              void* d_out, int out_size, void* d_ws, size_t ws_size,
                              hipStream_t stream){
  const float* inputs  = (const float*)d_in[0];
  const float* noise   = (const float*)d_in[1];
  const float* slot_mu = (const float*)d_in[2];
  const float* slot_ls = (const float*)d_in[3];
  const float* Wq   = (const float*)d_in[4];
  const float* bq   = (const float*)d_in[5];
  const float* Wk   = (const float*)d_in[6];
  const float* bk   = (const float*)d_in[7];
  const float* Wv   = (const float*)d_in[8];
  const float* bv   = (const float*)d_in[9];
  const float* W_ih = (const float*)d_in[10];
  const float* b_ih = (const float*)d_in[11];
  const float* W_hh = (const float*)d_in[12];
  const float* b_hh = (const float*)d_in[13];
  const float* ln_in_g = (const float*)d_in[14];
  const float* ln_in_b = (const float*)d_in[15];
  const float* ln_s_g  = (const float*)d_in[16];
  const float* ln_s_b  = (const float*)d_in[17];
  const float* ln_ff_g = (const float*)d_in[18];
  const float* ln_ff_b = (const float*)d_in[19];
  const float* W1 = (const float*)d_in[20];
  const float* b1 = (const float*)d_in[21];
  const float* W2 = (const float*)d_in[22];
  const float* b2 = (const float*)d_in[23];

  char* w = (char*)d_ws;
  auto alloc = [&](size_t n)->char*{ char* p=w; w += (n+255)&~(size_t)255; return p; };
  unsigned short* xc   = (unsigned short*)alloc(134217728);  // [B*N,256] bf16 LN'd cache
  float* upart         = (float*)alloc(8388608);             // [16,B,8,256] f32
  unsigned short* qp   = (unsigned short*)alloc(524288);     // [B,16,256] bf16
  float* sf            = (float*)alloc(524288);              // slots f32
  unsigned short* sb   = (unsigned short*)alloc(262144);     // slots bf16
  unsigned short* WcT  = (unsigned short*)alloc(131072);     // [256,256] bf16
  unsigned short* WvihT= (unsigned short*)alloc(393216);     // [768,256] bf16
  unsigned short* Whhb = (unsigned short*)alloc(393216);     // [768,256] bf16
  unsigned short* W1b  = (unsigned short*)alloc(262144);     // [512,256] bf16
  unsigned short* W2b  = (unsigned short*)alloc(262144);     // [256,512] bf16
  float* bc    = (float*)alloc(1024);
  float* wqbk  = (float*)alloc(1024);
  float* cbk   = (float*)alloc(256);
  float* bvih  = (float*)alloc(3072);
  float* dotb  = (float*)alloc(4096);
  float* asum  = (float*)alloc(2048);

  float* out_slots = (float*)d_out;
  float* out_attn  = out_slots + 131072;

  k_slots_init<<<dim3(512),dim3(256),0,stream>>>(noise, slot_mu, slot_ls, sf, sb);
  k_pre1<<<dim3(256),dim3(256),0,stream>>>(Wq, Wk, bq, bk, WcT, bc, wqbk, cbk);
  k_pre2<<<dim3(768),dim3(256),0,stream>>>(W_ih, Wv, bv, b_ih, WvihT, bvih);
  k_prep_b16<<<dim3(1792),dim3(256),0,stream>>>(W_hh, W1, W2, Whhb, W1b, W2b);
  k_slot_q<<<dim3(64),dim3(256),0,stream>>>(sf, ln_s_g, ln_s_b, WcT, bc, wqbk, cbk,
                                            qp, dotb, asum);

  for (int it=0; it<3; ++it){
    int last = (it==2);
    if (it==0){
      k_iter0<<<dim3(1024),dim3(256),0,stream>>>(
          inputs, ln_in_g, ln_in_b, qp, dotb, asum, upart, xc);
    } else {
      k_iter<<<dim3(1024),dim3(256),0,stream>>>(
          xc, qp, dotb, asum, upart,
          last ? out_attn : (float*)nullptr);
    }
    k_step<<<dim3(32),dim3(512),0,stream>>>(
        upart, asum, sf, sb, WvihT, bvih, Whhb, b_hh,
        ln_ff_g, ln_ff_b, W1b, b1, W2b, b2,
        ln_s_g, ln_s_b, WcT, bc, wqbk, cbk,
        qp, dotb, last ? out_slots : (float*)nullptr, last);
  }
}

// Round 4
// 841.671 us; speedup vs baseline: 1.0164x; 1.0164x over previous
//
#include <hip/hip_runtime.h>
#include <hip/hip_bf16.h>
#include <math.h>

// ---------- types & helpers ----------
typedef __bf16 bf16x8 __attribute__((ext_vector_type(8)));
typedef float f32x4 __attribute__((ext_vector_type(4)));

#define DEV static __device__ __forceinline__

DEV unsigned short f2b(float f){
  unsigned int u = __float_as_uint(f);
  u += 0x7fffu + ((u>>16)&1u);
  return (unsigned short)(u>>16);
}
DEV float b2f(unsigned short h){ return __uint_as_float(((unsigned int)h)<<16); }
DEV unsigned int pck(float a, float b){
  return (unsigned int)f2b(a) | ((unsigned int)f2b(b)<<16);
}
DEV f32x4 mfma16(bf16x8 a, bf16x8 b, f32x4 c){
  return __builtin_amdgcn_mfma_f32_16x16x32_bf16(a,b,c,0,0,0);
}
DEV float sigm(float x){ return 1.f/(1.f+expf(-x)); }
// n must be a compile-time constant after unrolling -> v_readlane_b32 (VALU pipe)
#define RDLANE(v, l) __uint_as_float(__builtin_amdgcn_readlane(__float_as_uint(v), (l)))

// ---------- I0: slots init ----------
__global__ __launch_bounds__(256) void k_slots_init(
    const float* __restrict__ noise, const float* __restrict__ mu,
    const float* __restrict__ ls, float* __restrict__ sf,
    unsigned short* __restrict__ sb){
  int i = blockIdx.x*256 + threadIdx.x;   // 131072 total
  int d = i & 255;
  float val = mu[d] + expf(ls[d]) * noise[i];
  sf[i] = val; sb[i] = f2b(val);
}

// ---------- prep: bf16 copies of W_hh, W1, W2 ----------
__global__ __launch_bounds__(256) void k_prep_b16(
    const float* __restrict__ Whh, const float* __restrict__ W1,
    const float* __restrict__ W2,
    unsigned short* __restrict__ Whhb, unsigned short* __restrict__ W1b,
    unsigned short* __restrict__ W2b){
  int i = blockIdx.x*256 + threadIdx.x;
  if (i < 196608) Whhb[i] = f2b(Whh[i]);
  else if (i < 327680) W1b[i-196608] = f2b(W1[i-196608]);
  else if (i < 458752) W2b[i-327680] = f2b(W2[i-327680]);
}

// ---------- P1 ----------
__global__ __launch_bounds__(256) void k_pre1(
    const float* __restrict__ Wq, const float* __restrict__ Wk,
    const float* __restrict__ bq, const float* __restrict__ bk,
    unsigned short* __restrict__ WcT, float* __restrict__ bc,
    float* __restrict__ wqbk, float* __restrict__ cbk){
  int c = blockIdx.x, d = threadIdx.x;
  float acc = 0.f;
  for (int e=0;e<256;e++)
    acc += Wq[e*256+d] * Wk[e*256+c];
  WcT[c*256+d] = f2b(acc);
  __shared__ float red[256];
  red[d] = bq[d] * Wk[d*256+c];
  __syncthreads();
  for (int s2=128;s2>0;s2>>=1){ if (d<s2) red[d]+=red[d+s2]; __syncthreads(); }
  if (d==0) bc[c] = red[0];
  if (blockIdx.x==0){
    float a2=0.f;
    for (int e=0;e<256;e++) a2 += Wq[e*256+d]*bk[e];
    wqbk[d] = a2;
    __syncthreads();
    red[d] = bq[d]*bk[d];
    __syncthreads();
    for (int s2=128;s2>0;s2>>=1){ if (d<s2) red[d]+=red[d+s2]; __syncthreads(); }
    if (d==0) cbk[0] = red[0];
  }
}

// ---------- P2 ----------
__global__ __launch_bounds__(256) void k_pre2(
    const float* __restrict__ W_ih, const float* __restrict__ Wv,
    const float* __restrict__ bv, const float* __restrict__ b_ih,
    unsigned short* __restrict__ WvihT, float* __restrict__ bvih){
  int j = blockIdx.x, c = threadIdx.x;
  float acc=0.f;
  for (int d=0; d<256; d++)
    acc += W_ih[j*256+d] * Wv[d*256+c];
  WvihT[j*256+c] = f2b(acc);
  __shared__ float red[256];
  red[c] = bv[c] * W_ih[j*256+c];
  __syncthreads();
  for (int s2=128;s2>0;s2>>=1){ if (c<s2) red[c]+=red[c+s2]; __syncthreads(); }
  if (c==0) bvih[j] = red[0] + b_ih[j];
}

// ---------- I1: sn=LN(slots); q' = sn@Wc + bc; dotbias; zero attn_sum ----------
__global__ __launch_bounds__(256) void k_slot_q(
    const float* __restrict__ sf, const float* __restrict__ g,
    const float* __restrict__ be,
    const unsigned short* __restrict__ WcT, const float* __restrict__ bc,
    const float* __restrict__ wqbk, const float* __restrict__ cbk,
    unsigned short* __restrict__ qp, float* __restrict__ dotbias,
    float* __restrict__ attn_sum){
  __shared__ __align__(16) unsigned short sn[16][264];
  int b = blockIdx.x, t = threadIdx.x;
  if (t < 8) attn_sum[b*8+t] = 0.f;
  if (t < 8) dotbias[b*16+8+t] = 0.f;
  int r = t>>5, j = t&31;
  const float* pr = sf + (b*8+r)*256 + j*8;
  float v[8]; float s=0.f;
  #pragma unroll
  for (int i=0;i<8;i++){ v[i]=pr[i]; s+=v[i]; }
  s += __shfl_xor(s,1); s+=__shfl_xor(s,2); s+=__shfl_xor(s,4);
  s += __shfl_xor(s,8); s+=__shfl_xor(s,16);
  float m = s*(1.f/256.f);
  float vs=0.f;
  #pragma unroll
  for (int i=0;i<8;i++){ float d = v[i]-m; vs += d*d; }
  vs += __shfl_xor(vs,1); vs+=__shfl_xor(vs,2); vs+=__shfl_xor(vs,4);
  vs += __shfl_xor(vs,8); vs+=__shfl_xor(vs,16);
  float rstd = rsqrtf(vs*(1.f/256.f) + 1e-5f);
  float dp = 0.f;
  #pragma unroll
  for (int i=0;i<8;i++){
    int d = j*8+i;
    float snv = (v[i]-m)*rstd*g[d] + be[d];
    sn[r][d] = f2b(snv);
    dp += snv * wqbk[d];
  }
  dp += __shfl_xor(dp,1); dp+=__shfl_xor(dp,2); dp+=__shfl_xor(dp,4);
  dp += __shfl_xor(dp,8); dp+=__shfl_xor(dp,16);
  if (j==0) dotbias[b*16+r] = dp + cbk[0];
  for (int rr=8; rr<16; ++rr){ sn[rr][t]=0; if (t<8) sn[rr][256+t]=0; }
  __syncthreads();
  int lane = t&63, wv = t>>6, l16 = lane&15, quad = lane>>4;
  #pragma unroll
  for (int nt=0; nt<4; ++nt){
    int col = (wv*4+nt)*16 + l16;
    f32x4 acc = {0.f,0.f,0.f,0.f};
    #pragma unroll
    for (int kk=0;kk<8;kk++){
      int kd = kk*32 + quad*8;
      bf16x8 a = *(const bf16x8*)&sn[l16][kd];
      bf16x8 bb = *(const bf16x8*)(WcT + col*256 + kd);
      acc = mfma16(a,bb,acc);
    }
    float bcv = bc[col];
    #pragma unroll
    for (int ri=0;ri<4;ri++){
      int rw = quad*4+ri;
      qp[(b*16+rw)*256 + col] = f2b(acc[ri] + bcv);
    }
  }
}

// ---------- I2a (iteration 0): fused LN + dots + softmax + partial u ----------
// grid = 64 batches x 16 chunks = 1024 blocks, 4 tiles of 64 tokens each.
// Stage 3: column-owner (c = t, acc8[8] regs); attn via areg[8] (al row in
// registers) + v_readlane -> no LDS broadcasts, summation order == round 2.
__global__ __launch_bounds__(256) void k_iter0(
    const float* __restrict__ in, const float* __restrict__ g,
    const float* __restrict__ be, const unsigned short* __restrict__ qp,
    const float* __restrict__ dotbias, float* __restrict__ attn_sum,
    float* __restrict__ upart, unsigned short* __restrict__ xc_w){
  __shared__ __align__(16) unsigned short xt[64][264];
  __shared__ __align__(16) float al[64][8];
  int t = threadIdx.x;
  int b = blockIdx.x >> 4, sp = blockIdx.x & 15;
  int lane=t&63, wv=t>>6, l16=lane&15, quad=lane>>4;
  bf16x8 aq[8];
  #pragma unroll
  for (int kk=0;kk<8;kk++)
    aq[kk] = *(const bf16x8*)(qp + ((size_t)(b*16+l16))*256 + kk*32+quad*8);
  float db[4];
  #pragma unroll
  for (int ri=0;ri<4;ri++) db[ri] = dotbias[b*16 + quad*4 + ri];
  float acc8[8] = {0.f,0.f,0.f,0.f,0.f,0.f,0.f,0.f};
  float rbs[4] = {0.f,0.f,0.f,0.f};
  int rl = t>>3, j = t&7;
  for (int tile=0; tile<4; ++tile){
    int n0 = sp*256 + tile*64;
    __syncthreads();   // xt/al free from previous tile's readers
    // --- stage 1: LN(inputs) -> LDS bf16 + global bf16 cache ---
    #pragma unroll
    for (int p=0;p<2;p++){
      int row = p*32 + rl;
      const float* pr = in + ((size_t)(b*4096 + n0 + row))*256 + j*32;
      float v[32]; float s=0.f;
      #pragma unroll
      for (int c=0;c<8;c++) *(float4*)(v+c*4) = *(const float4*)(pr + c*4);
      #pragma unroll
      for (int i=0;i<32;i++) s += v[i];
      s += __shfl_xor(s,1); s+=__shfl_xor(s,2); s+=__shfl_xor(s,4);
      float m = s*(1.f/256.f);
      float vs=0.f;
      #pragma unroll
      for (int i=0;i<32;i++){ float d=v[i]-m; vs+=d*d; }
      vs+=__shfl_xor(vs,1); vs+=__shfl_xor(vs,2); vs+=__shfl_xor(vs,4);
      float rstd = rsqrtf(vs*(1.f/256.f)+1e-5f);
      #pragma unroll
      for (int c=0;c<4;c++){
        float o[8];
        #pragma unroll
        for (int q=0;q<8;q++){
          int d = j*32 + c*8 + q;
          o[q] = (v[c*8+q]-m)*rstd*g[d] + be[d];
        }
        uint4 w4;
        w4.x=pck(o[0],o[1]); w4.y=pck(o[2],o[3]);
        w4.z=pck(o[4],o[5]); w4.w=pck(o[6],o[7]);
        *(uint4*)&xt[row][j*32 + c*8] = w4;
        *(uint4*)(xc_w + ((size_t)(b*4096 + n0 + row))*256 + j*32 + c*8) = w4;
      }
    }
    __syncthreads();
    // --- stage 2: dots + softmax over slots ---
    f32x4 dacc = {0.f,0.f,0.f,0.f};
    #pragma unroll
    for (int kk=0;kk<8;kk++){
      int kd = kk*32 + quad*8;
      bf16x8 bb = *(const bf16x8*)&xt[wv*16 + l16][kd];
      dacc = mfma16(aq[kk],bb,dacc);
    }
    const float scale = 0.0625f;
    float val[4];
    #pragma unroll
    for (int ri=0;ri<4;ri++) val[ri] = (dacc[ri] + db[ri]) * scale;
    float mx = fmaxf(fmaxf(val[0],val[1]), fmaxf(val[2],val[3]));
    mx = fmaxf(mx, __shfl_xor(mx,16));
    float e[4], s4=0.f;
    #pragma unroll
    for (int ri=0;ri<4;ri++){ e[ri] = expf(val[ri]-mx); s4 += e[ri]; }
    float s8 = s4 + __shfl_xor(s4,16);
    float inv = 1.f/s8;
    float av[4];
    #pragma unroll
    for (int ri=0;ri<4;ri++) av[ri] = e[ri]*inv;
    if (quad < 2){
      int nl = wv*16 + l16;
      #pragma unroll
      for (int ri=0;ri<4;ri++){
        al[nl][quad*4+ri] = av[ri];
        float ss = av[ri];
        ss += __shfl_xor(ss,1); ss+=__shfl_xor(ss,2);
        ss += __shfl_xor(ss,4); ss+=__shfl_xor(ss,8);
        if (l16==0) rbs[ri] += ss;
      }
    }
    __syncthreads();
    // --- stage 3: column-owner accumulate; attn via readlane from areg ---
    float areg[8];
    *(float4*)&areg[0] = *(const float4*)&al[lane][0];
    *(float4*)&areg[4] = *(const float4*)&al[lane][4];
    #pragma unroll
    for (int n=0;n<64;++n){
      float xv = b2f(xt[n][t]);
      acc8[0] += RDLANE(areg[0], n) * xv;
      acc8[1] += RDLANE(areg[1], n) * xv;
      acc8[2] += RDLANE(areg[2], n) * xv;
      acc8[3] += RDLANE(areg[3], n) * xv;
      acc8[4] += RDLANE(areg[4], n) * xv;
      acc8[5] += RDLANE(areg[5], n) * xv;
      acc8[6] += RDLANE(areg[6], n) * xv;
      acc8[7] += RDLANE(areg[7], n) * xv;
    }
  }
  float* o = upart + (size_t)sp*131072 + ((size_t)b*8)*256 + t;
  #pragma unroll
  for (int k2=0;k2<8;k2++) o[(size_t)k2*256] = acc8[k2];
  if (quad < 2 && l16 == 0){
    #pragma unroll
    for (int ri=0;ri<4;ri++)
      atomicAdd(&attn_sum[b*8 + quad*4 + ri], rbs[ri]);
  }
}

// ---------- I2b (iterations 1,2): bf16 cache, register-prefetched ----------
__global__ __launch_bounds__(256) void k_iter(
    const unsigned short* __restrict__ xc,
    const unsigned short* __restrict__ qp,
    const float* __restrict__ dotbias, float* __restrict__ attn_sum,
    float* __restrict__ upart, float* __restrict__ attn_out){
  __shared__ __align__(16) unsigned short xt[64][264];
  __shared__ __align__(16) float al[64][8];
  int t = threadIdx.x;
  int b = blockIdx.x >> 4, sp = blockIdx.x & 15;
  int lane=t&63, wv=t>>6, l16=lane&15, quad=lane>>4;
  bf16x8 aq[8];
  #pragma unroll
  for (int kk=0;kk<8;kk++)
    aq[kk] = *(const bf16x8*)(qp + ((size_t)(b*16+l16))*256 + kk*32+quad*8);
  float db[4];
  #pragma unroll
  for (int ri=0;ri<4;ri++) db[ri] = dotbias[b*16 + quad*4 + ri];
  float acc8[8] = {0.f,0.f,0.f,0.f,0.f,0.f,0.f,0.f};
  float rbs[4] = {0.f,0.f,0.f,0.f};
  int rl = t>>3, j = t&7;
  const unsigned short* cbase = xc + ((size_t)(b*4096 + sp*256))*256;
  uint4 R[8];
  #pragma unroll
  for (int p=0;p<2;p++){
    const unsigned short* pr = cbase + (size_t)(p*32+rl)*256 + j*32;
    #pragma unroll
    for (int c=0;c<4;c++) R[p*4+c] = *(const uint4*)(pr + c*8);
  }
  for (int tile=0; tile<4; ++tile){
    // --- stage 1: dump prefetched registers into LDS ---
    #pragma unroll
    for (int p=0;p<2;p++){
      #pragma unroll
      for (int c=0;c<4;c++)
        *(uint4*)&xt[p*32+rl][j*32 + c*8] = R[p*4+c];
    }
    __syncthreads();
    if (tile<3){
      const unsigned short* nb = cbase + (size_t)(tile+1)*64*256;
      #pragma unroll
      for (int p=0;p<2;p++){
        const unsigned short* pr = nb + (size_t)(p*32+rl)*256 + j*32;
        #pragma unroll
        for (int c=0;c<4;c++) R[p*4+c] = *(const uint4*)(pr + c*8);
      }
    }
    int n0 = sp*256 + tile*64;
    // --- stage 2: dots + softmax ---
    f32x4 dacc = {0.f,0.f,0.f,0.f};
    #pragma unroll
    for (int kk=0;kk<8;kk++){
      int kd = kk*32 + quad*8;
      bf16x8 bb = *(const bf16x8*)&xt[wv*16 + l16][kd];
      dacc = mfma16(aq[kk],bb,dacc);
    }
    const float scale = 0.0625f;
    float val[4];
    #pragma unroll
    for (int ri=0;ri<4;ri++) val[ri] = (dacc[ri] + db[ri]) * scale;
    float mx = fmaxf(fmaxf(val[0],val[1]), fmaxf(val[2],val[3]));
    mx = fmaxf(mx, __shfl_xor(mx,16));
    float e[4], s4=0.f;
    #pragma unroll
    for (int ri=0;ri<4;ri++){ e[ri] = expf(val[ri]-mx); s4 += e[ri]; }
    float s8 = s4 + __shfl_xor(s4,16);
    float inv = 1.f/s8;
    float av[4];
    #pragma unroll
    for (int ri=0;ri<4;ri++) av[ri] = e[ri]*inv;
    if (quad < 2){
      int nl = wv*16 + l16;
      #pragma unroll
      for (int ri=0;ri<4;ri++){
        int kr = quad*4+ri;
        al[nl][kr] = av[ri];
        if (attn_out)
          attn_out[((size_t)(b*8+kr))*4096 + n0 + nl] = av[ri];
        float ss = av[ri];
        ss += __shfl_xor(ss,1); ss+=__shfl_xor(ss,2);
        ss += __shfl_xor(ss,4); ss+=__shfl_xor(ss,8);
        if (l16==0) rbs[ri] += ss;
      }
    }
    __syncthreads();
    // --- stage 3: column-owner accumulate; attn via readlane from areg ---
    float areg[8];
    *(float4*)&areg[0] = *(const float4*)&al[lane][0];
    *(float4*)&areg[4] = *(const float4*)&al[lane][4];
    #pragma unroll
    for (int n=0;n<64;++n){
      float xv = b2f(xt[n][t]);
      acc8[0] += RDLANE(areg[0], n) * xv;
      acc8[1] += RDLANE(areg[1], n) * xv;
      acc8[2] += RDLANE(areg[2], n) * xv;
      acc8[3] += RDLANE(areg[3], n) * xv;
      acc8[4] += RDLANE(areg[4], n) * xv;
      acc8[5] += RDLANE(areg[5], n) * xv;
      acc8[6] += RDLANE(areg[6], n) * xv;
      acc8[7] += RDLANE(areg[7], n) * xv;
    }
    __syncthreads();   // xt/al consumed; safe to overwrite next tile
  }
  float* o = upart + (size_t)sp*131072 + ((size_t)b*8)*256 + t;
  #pragma unroll
  for (int k2=0;k2<8;k2++) o[(size_t)k2*256] = acc8[k2];
  if (quad < 2 && l16 == 0){
    #pragma unroll
    for (int ri=0;ri<4;ri++)
      atomicAdd(&attn_sum[b*8 + quad*4 + ri], rbs[ri]);
  }
}

// ---------- I3 fused slot chain: 32 blocks x 1024 threads (16 waves) ----------
// Each block: 2 batches = 16 slot rows; every GEMM's column space split
// across 16 waves (half the per-wave MFMA chain of the 8-wave version).
__global__ __launch_bounds__(1024) void k_step(
    const float* __restrict__ upart, float* __restrict__ asum,
    float* __restrict__ sf, unsigned short* __restrict__ sb,
    const unsigned short* __restrict__ WvihT, const float* __restrict__ bvih,
    const unsigned short* __restrict__ Whhb, const float* __restrict__ bhh,
    const float* __restrict__ lnffg, const float* __restrict__ lnffb,
    const unsigned short* __restrict__ W1b, const float* __restrict__ b1,
    const unsigned short* __restrict__ W2b, const float* __restrict__ b2v,
    const float* __restrict__ lnsg, const float* __restrict__ lnsb,
    const unsigned short* __restrict__ WcT, const float* __restrict__ bc,
    const float* __restrict__ wqbk, const float* __restrict__ cbk,
    unsigned short* __restrict__ qp, float* __restrict__ dotb,
    float* __restrict__ out_slots, int last){
  __shared__ __align__(16) unsigned short ub16[16][264];
  __shared__ __align__(16) float hls[16][268];
  __shared__ __align__(16) unsigned short sn[16][264];
  __shared__ __align__(16) unsigned short s1t[16][520];
  __shared__ float redh[16][16], redq[16][16], mr[16], rs[16];
  int t = threadIdx.x;
  int Bk = blockIdx.x;                 // batches 2*Bk, 2*Bk+1
  int bb0 = Bk*2;
  int lane=t&63, wv=t>>6, l16=lane&15, quad=lane>>4;
  // --- stage A: reduce upart (16 slices), normalize, to LDS bf16 ---
  {
    int r16 = t>>6, c0 = (t&63)*4;
    size_t base = ((size_t)(Bk*16 + r16))*256 + c0;
    float4 a0={0,0,0,0};
    #pragma unroll
    for (int sp2=0; sp2<16; ++sp2){
      const float* p = upart + (size_t)sp2*131072 + base;
      float4 u0=*(const float4*)p;
      a0.x+=u0.x;a0.y+=u0.y;a0.z+=u0.z;a0.w+=u0.w;
    }
    float inv = 1.f/(asum[Bk*16 + r16] + 1e-8f);
    *(unsigned int*)&ub16[r16][c0]   = pck(a0.x*inv, a0.y*inv);
    *(unsigned int*)&ub16[r16][c0+2] = pck(a0.z*inv, a0.w*inv);
  }
  __syncthreads();
  if (t < 16) asum[Bk*16 + t] = 0.f;
  // --- stage B: gates via MFMA + GRU elementwise (1 col-tile per wave) ---
  bf16x8 afi[8], afh[8];
  #pragma unroll
  for (int kk=0;kk<8;kk++){
    int kd = kk*32+quad*8;
    afi[kk] = *(const bf16x8*)&ub16[l16][kd];
    afh[kk] = *(const bf16x8*)(sb + ((size_t)(Bk*16+l16))*256 + kd);
  }
  float sh[4]={0,0,0,0}, sq[4]={0,0,0,0};
  {
    int dR = wv*16 + l16;
    f32x4 cIR={0,0,0,0}, cIZ={0,0,0,0}, cIN={0,0,0,0};
    f32x4 cHR={0,0,0,0}, cHZ={0,0,0,0}, cHN={0,0,0,0};
    #pragma unroll
    for (int kk=0;kk<8;kk++){
      int kd = kk*32+quad*8;
      cIR = mfma16(afi[kk], *(const bf16x8*)(WvihT + (size_t)dR*256 + kd), cIR);
      cIZ = mfma16(afi[kk], *(const bf16x8*)(WvihT + (size_t)(256+dR)*256 + kd), cIZ);
      cIN = mfma16(afi[kk], *(const bf16x8*)(WvihT + (size_t)(512+dR)*256 + kd), cIN);
      cHR = mfma16(afh[kk], *(const bf16x8*)(Whhb + (size_t)dR*256 + kd), cHR);
      cHZ = mfma16(afh[kk], *(const bf16x8*)(Whhb + (size_t)(256+dR)*256 + kd), cHZ);
      cHN = mfma16(afh[kk], *(const bf16x8*)(Whhb + (size_t)(512+dR)*256 + kd), cHN);
    }
    float biR = bvih[dR], biZ = bvih[256+dR], biN = bvih[512+dR];
    float bhR = bhh[dR], bhZ = bhh[256+dR], bhN = bhh[512+dR];
    #pragma unroll
    for (int ri=0;ri<4;ri++){
      int row = quad*4+ri;
      float hp = sf[((size_t)(Bk*16+row))*256 + dR];
      float rg = sigm(cIR[ri]+biR + cHR[ri]+bhR);
      float z  = sigm(cIZ[ri]+biZ + cHZ[ri]+bhZ);
      float nn = tanhf(cIN[ri]+biN + rg*(cHN[ri]+bhN));
      float h = (1.f-z)*nn + z*hp;
      hls[row][dR] = h;
      sh[ri] += h; sq[ri] += h*h;
    }
  }
  #pragma unroll
  for (int ri=0;ri<4;ri++){
    sh[ri]+=__shfl_xor(sh[ri],1); sh[ri]+=__shfl_xor(sh[ri],2);
    sh[ri]+=__shfl_xor(sh[ri],4); sh[ri]+=__shfl_xor(sh[ri],8);
    sq[ri]+=__shfl_xor(sq[ri],1); sq[ri]+=__shfl_xor(sq[ri],2);
    sq[ri]+=__shfl_xor(sq[ri],4); sq[ri]+=__shfl_xor(sq[ri],8);
  }
  if (l16==0){
    #pragma unroll
    for (int ri=0;ri<4;ri++){
      redh[wv][quad*4+ri] = sh[ri];
      redq[wv][quad*4+ri] = sq[ri];
    }
  }
  __syncthreads();
  if (t < 16){
    float s = 0.f, q = 0.f;
    #pragma unroll
    for (int w2=0;w2<16;w2++){ s += redh[w2][t]; q += redq[w2][t]; }
    float m = s*(1.f/256.f);
    float var = q*(1.f/256.f) - m*m;
    mr[t] = m; rs[t] = rsqrtf(var + 1e-5f);
  }
  __syncthreads();
  // --- stage C: ff = LN(h) (bf16 into sn) ---
  {
    int row = t>>6, c0 = (t&63)*4;
    float m = mr[row], rstd = rs[row];
    float o0 = (hls[row][c0+0]-m)*rstd*lnffg[c0+0] + lnffb[c0+0];
    float o1 = (hls[row][c0+1]-m)*rstd*lnffg[c0+1] + lnffb[c0+1];
    float o2 = (hls[row][c0+2]-m)*rstd*lnffg[c0+2] + lnffb[c0+2];
    float o3 = (hls[row][c0+3]-m)*rstd*lnffg[c0+3] + lnffb[c0+3];
    *(unsigned int*)&sn[row][c0]   = pck(o0,o1);
    *(unsigned int*)&sn[row][c0+2] = pck(o2,o3);
  }
  __syncthreads();
  // --- stage D: s1 = relu(ff@W1^T + b1), 32 col-tiles over 16 waves ---
  {
    bf16x8 af[8];
    #pragma unroll
    for (int kk=0;kk<8;kk++)
      af[kk] = *(const bf16x8*)&sn[l16][kk*32+quad*8];
    #pragma unroll
    for (int ct=wv*2; ct<wv*2+2; ++ct){
      int col = ct*16+l16;
      f32x4 acc={0,0,0,0};
      #pragma unroll
      for (int kk=0;kk<8;kk++)
        acc = mfma16(af[kk], *(const bf16x8*)(W1b + (size_t)col*256 + kk*32+quad*8), acc);
      float bb = b1[col];
      #pragma unroll
      for (int ri=0;ri<4;ri++){
        float v2 = acc[ri]+bb; v2 = v2>0.f? v2:0.f;
        s1t[quad*4+ri][col] = f2b(v2);
      }
    }
  }
  __syncthreads();
  // --- stage E: slots = h + s1@W2^T + b2, 16 col-tiles over 16 waves ---
  {
    bf16x8 af[16];
    #pragma unroll
    for (int kk=0;kk<16;kk++)
      af[kk] = *(const bf16x8*)&s1t[l16][kk*32+quad*8];
    int col = wv*16+l16;
    f32x4 acc={0,0,0,0};
    #pragma unroll
    for (int kk=0;kk<16;kk++)
      acc = mfma16(af[kk], *(const bf16x8*)(W2b + (size_t)col*512 + kk*32+quad*8), acc);
    float bb = b2v[col];
    #pragma unroll
    for (int ri=0;ri<4;ri++){
      int row = quad*4+ri;
      float v2 = acc[ri] + bb + hls[row][col];
      size_t gidx = ((size_t)(Bk*16+row))*256 + col;
      sf[gidx] = v2;
      sb[gidx] = f2b(v2);
      if (last) out_slots[gidx] = v2;
      hls[row][col] = v2;
    }
  }
  if (!last){
    __syncthreads();
    // --- stage F: LN(new slots) + dotbias + q' for next iteration ---
    {
      int row = t>>6, c0 = (t&63)*4;
      float hv[4];
      float ps=0.f, pq=0.f;
      #pragma unroll
      for (int c=0;c<4;c++){ hv[c]=hls[row][c0+c]; ps+=hv[c]; pq+=hv[c]*hv[c]; }
      ps+=__shfl_xor(ps,1); ps+=__shfl_xor(ps,2); ps+=__shfl_xor(ps,4);
      ps+=__shfl_xor(ps,8); ps+=__shfl_xor(ps,16); ps+=__shfl_xor(ps,32);
      pq+=__shfl_xor(pq,1); pq+=__shfl_xor(pq,2); pq+=__shfl_xor(pq,4);
      pq+=__shfl_xor(pq,8); pq+=__shfl_xor(pq,16); pq+=__shfl_xor(pq,32);
      float m = ps*(1.f/256.f);
      float var = pq*(1.f/256.f) - m*m;
      float rstd = rsqrtf(var + 1e-5f);
      float dp = 0.f;
      float o0 = (hv[0]-m)*rstd*lnsg[c0+0] + lnsb[c0+0];
      float o1 = (hv[1]-m)*rstd*lnsg[c0+1] + lnsb[c0+1];
      float o2 = (hv[2]-m)*rstd*lnsg[c0+2] + lnsb[c0+2];
      float o3 = (hv[3]-m)*rstd*lnsg[c0+3] + lnsb[c0+3];
      dp += o0*wqbk[c0+0] + o1*wqbk[c0+1] + o2*wqbk[c0+2] + o3*wqbk[c0+3];
      *(unsigned int*)&sn[row][c0]   = pck(o0,o1);
      *(unsigned int*)&sn[row][c0+2] = pck(o2,o3);
      dp+=__shfl_xor(dp,1); dp+=__shfl_xor(dp,2); dp+=__shfl_xor(dp,4);
      dp+=__shfl_xor(dp,8); dp+=__shfl_xor(dp,16); dp+=__shfl_xor(dp,32);
      if ((t&63)==0){
        int bloc = row>>3, rr = row&7;
        dotb[(bb0+bloc)*16 + rr] = dp + cbk[0];
      }
    }
    __syncthreads();
    {
      bf16x8 af[8];
      #pragma unroll
      for (int kk=0;kk<8;kk++)
        af[kk] = *(const bf16x8*)&sn[l16][kk*32+quad*8];
      int col = wv*16+l16;
      f32x4 acc={0,0,0,0};
      #pragma unroll
      for (int kk=0;kk<8;kk++)
        acc = mfma16(af[kk], *(const bf16x8*)(WcT + (size_t)col*256 + kk*32+quad*8), acc);
      float bcv = bc[col];
      #pragma unroll
      for (int ri=0;ri<4;ri++){
        int row = quad*4+ri;
        int bloc = row>>3, rr = row&7;
        qp[((size_t)((bb0+bloc)*16 + rr))*256 + col] = f2b(acc[ri] + bcv);
      }
    }
  }
}

// ---------- launch ----------
extern "C" void kernel_launch(void* const* d_in, const int* in_sizes, int n_in,
                              void* d_out, int out_size, void* d_ws, size_t ws_size,
                              hipStream_t stream){
  const float* inputs  = (const float*)d_in[0];
  const float* noise   = (const float*)d_in[1];
  const float* slot_mu = (const float*)d_in[2];
  const float* slot_ls = (const float*)d_in[3];
  const float* Wq   = (const float*)d_in[4];
  const float* bq   = (const float*)d_in[5];
  const float* Wk   = (const float*)d_in[6];
  const float* bk   = (const float*)d_in[7];
  const float* Wv   = (const float*)d_in[8];
  const float* bv   = (const float*)d_in[9];
  const float* W_ih = (const float*)d_in[10];
  const float* b_ih = (const float*)d_in[11];
  const float* W_hh = (const float*)d_in[12];
  const float* b_hh = (const float*)d_in[13];
  const float* ln_in_g = (const float*)d_in[14];
  const float* ln_in_b = (const float*)d_in[15];
  const float* ln_s_g  = (const float*)d_in[16];
  const float* ln_s_b  = (const float*)d_in[17];
  const float* ln_ff_g = (const float*)d_in[18];
  const float* ln_ff_b = (const float*)d_in[19];
  const float* W1 = (const float*)d_in[20];
  const float* b1 = (const float*)d_in[21];
  const float* W2 = (const float*)d_in[22];
  const float* b2 = (const float*)d_in[23];

  char* w = (char*)d_ws;
  auto alloc = [&](size_t n)->char*{ char* p=w; w += (n+255)&~(size_t)255; return p; };
  unsigned short* xc   = (unsigned short*)alloc(134217728);  // [B*N,256] bf16 LN'd cache
  float* upart         = (float*)alloc(8388608);             // [16,B,8,256] f32
  unsigned short* qp   = (unsigned short*)alloc(524288);     // [B,16,256] bf16
  float* sf            = (float*)alloc(524288);              // slots f32
  unsigned short* sb   = (unsigned short*)alloc(262144);     // slots bf16
  unsigned short* WcT  = (unsigned short*)alloc(131072);     // [256,256] bf16
  unsigned short* WvihT= (unsigned short*)alloc(393216);     // [768,256] bf16
  unsigned short* Whhb = (unsigned short*)alloc(393216);     // [768,256] bf16
  unsigned short* W1b  = (unsigned short*)alloc(262144);     // [512,256] bf16
  unsigned short* W2b  = (unsigned short*)alloc(262144);     // [256,512] bf16
  float* bc    = (float*)alloc(1024);
  float* wqbk  = (float*)alloc(1024);
  float* cbk   = (float*)alloc(256);
  float* bvih  = (float*)alloc(3072);
  float* dotb  = (float*)alloc(4096);
  float* asum  = (float*)alloc(2048);

  float* out_slots = (float*)d_out;
  float* out_attn  = out_slots + 131072;

  k_slots_init<<<dim3(512),dim3(256),0,stream>>>(noise, slot_mu, slot_ls, sf, sb);
  k_pre1<<<dim3(256),dim3(256),0,stream>>>(Wq, Wk, bq, bk, WcT, bc, wqbk, cbk);
  k_pre2<<<dim3(768),dim3(256),0,stream>>>(W_ih, Wv, bv, b_ih, WvihT, bvih);
  k_prep_b16<<<dim3(1792),dim3(256),0,stream>>>(W_hh, W1, W2, Whhb, W1b, W2b);
  k_slot_q<<<dim3(64),dim3(256),0,stream>>>(sf, ln_s_g, ln_s_b, WcT, bc, wqbk, cbk,
                                            qp, dotb, asum);

  for (int it=0; it<3; ++it){
    int last = (it==2);
    if (it==0){
      k_iter0<<<dim3(1024),dim3(256),0,stream>>>(
          inputs, ln_in_g, ln_in_b, qp, dotb, asum, upart, xc);
    } else {
      k_iter<<<dim3(1024),dim3(256),0,stream>>>(
          xc, qp, dotb, asum, upart,
          last ? out_attn : (float*)nullptr);
    }
    k_step<<<dim3(32),dim3(1024),0,stream>>>(
        upart, asum, sf, sb, WvihT, bvih, Whhb, b_hh,
        ln_ff_g, ln_ff_b, W1b, b1, W2b, b2,
        ln_s_g, ln_s_b, WcT, bc, wqbk, cbk,
        qp, dotb, last ? out_slots : (float*)nullptr, last);
  }
}

// Round 5
// 717.883 us; speedup vs baseline: 1.1917x; 1.1724x over previous
//
#include <hip/hip_runtime.h>
#include <hip/hip_bf16.h>
#include <math.h>

// ---------- types & helpers ----------
typedef __bf16 bf16x8 __attribute__((ext_vector_type(8)));
typedef float f32x4 __attribute__((ext_vector_type(4)));

#define DEV static __device__ __forceinline__

DEV unsigned short f2b(float f){
  unsigned int u = __float_as_uint(f);
  u += 0x7fffu + ((u>>16)&1u);
  return (unsigned short)(u>>16);
}
DEV float b2f(unsigned short h){ return __uint_as_float(((unsigned int)h)<<16); }
DEV unsigned int pck(float a, float b){
  return (unsigned int)f2b(a) | ((unsigned int)f2b(b)<<16);
}
DEV f32x4 mfma16(bf16x8 a, bf16x8 b, f32x4 c){
  return __builtin_amdgcn_mfma_f32_16x16x32_bf16(a,b,c,0,0,0);
}
DEV float sigm(float x){ return 1.f/(1.f+expf(-x)); }

// subtiled LDS x-tile: [nblk 16][cblk 16][4 n][16 d], strides chosen so
// nblk -> +4 banks, cblk -> +4 banks, rows 16B-aligned.
// elem index for (token n in 0..63, feature d in 0..255):
DEV int xti(int n, int d){
  return (n>>2)*1160 + (d>>4)*72 + (n&3)*16 + (d&15);
}
#define XT_ELEMS 18560   // 16*1160

// ---------- I0: slots init ----------
__global__ __launch_bounds__(256) void k_slots_init(
    const float* __restrict__ noise, const float* __restrict__ mu,
    const float* __restrict__ ls, float* __restrict__ sf,
    unsigned short* __restrict__ sb){
  int i = blockIdx.x*256 + threadIdx.x;   // 131072 total
  int d = i & 255;
  float val = mu[d] + expf(ls[d]) * noise[i];
  sf[i] = val; sb[i] = f2b(val);
}

// ---------- prep: bf16 copies of W_hh, W1, W2 ----------
__global__ __launch_bounds__(256) void k_prep_b16(
    const float* __restrict__ Whh, const float* __restrict__ W1,
    const float* __restrict__ W2,
    unsigned short* __restrict__ Whhb, unsigned short* __restrict__ W1b,
    unsigned short* __restrict__ W2b){
  int i = blockIdx.x*256 + threadIdx.x;
  if (i < 196608) Whhb[i] = f2b(Whh[i]);
  else if (i < 327680) W1b[i-196608] = f2b(W1[i-196608]);
  else if (i < 458752) W2b[i-327680] = f2b(W2[i-327680]);
}

// ---------- P1 ----------
__global__ __launch_bounds__(256) void k_pre1(
    const float* __restrict__ Wq, const float* __restrict__ Wk,
    const float* __restrict__ bq, const float* __restrict__ bk,
    unsigned short* __restrict__ WcT, float* __restrict__ bc,
    float* __restrict__ wqbk, float* __restrict__ cbk){
  int c = blockIdx.x, d = threadIdx.x;
  float acc = 0.f;
  for (int e=0;e<256;e++)
    acc += Wq[e*256+d] * Wk[e*256+c];
  WcT[c*256+d] = f2b(acc);
  __shared__ float red[256];
  red[d] = bq[d] * Wk[d*256+c];
  __syncthreads();
  for (int s2=128;s2>0;s2>>=1){ if (d<s2) red[d]+=red[d+s2]; __syncthreads(); }
  if (d==0) bc[c] = red[0];
  if (blockIdx.x==0){
    float a2=0.f;
    for (int e=0;e<256;e++) a2 += Wq[e*256+d]*bk[e];
    wqbk[d] = a2;
    __syncthreads();
    red[d] = bq[d]*bk[d];
    __syncthreads();
    for (int s2=128;s2>0;s2>>=1){ if (d<s2) red[d]+=red[d+s2]; __syncthreads(); }
    if (d==0) cbk[0] = red[0];
  }
}

// ---------- P2 ----------
__global__ __launch_bounds__(256) void k_pre2(
    const float* __restrict__ W_ih, const float* __restrict__ Wv,
    const float* __restrict__ bv, const float* __restrict__ b_ih,
    unsigned short* __restrict__ WvihT, float* __restrict__ bvih){
  int j = blockIdx.x, c = threadIdx.x;
  float acc=0.f;
  for (int d=0; d<256; d++)
    acc += W_ih[j*256+d] * Wv[d*256+c];
  WvihT[j*256+c] = f2b(acc);
  __shared__ float red[256];
  red[c] = bv[c] * W_ih[j*256+c];
  __syncthreads();
  for (int s2=128;s2>0;s2>>=1){ if (c<s2) red[c]+=red[c+s2]; __syncthreads(); }
  if (c==0) bvih[j] = red[0] + b_ih[j];
}

// ---------- I1: sn=LN(slots); q' = sn@Wc + bc; dotbias; zero attn_sum ----------
__global__ __launch_bounds__(256) void k_slot_q(
    const float* __restrict__ sf, const float* __restrict__ g,
    const float* __restrict__ be,
    const unsigned short* __restrict__ WcT, const float* __restrict__ bc,
    const float* __restrict__ wqbk, const float* __restrict__ cbk,
    unsigned short* __restrict__ qp, float* __restrict__ dotbias,
    float* __restrict__ attn_sum){
  __shared__ __align__(16) unsigned short sn[16][264];
  int b = blockIdx.x, t = threadIdx.x;
  if (t < 8) attn_sum[b*8+t] = 0.f;
  if (t < 8) dotbias[b*16+8+t] = 0.f;
  int r = t>>5, j = t&31;
  const float* pr = sf + (b*8+r)*256 + j*8;
  float v[8]; float s=0.f;
  #pragma unroll
  for (int i=0;i<8;i++){ v[i]=pr[i]; s+=v[i]; }
  s += __shfl_xor(s,1); s+=__shfl_xor(s,2); s+=__shfl_xor(s,4);
  s += __shfl_xor(s,8); s+=__shfl_xor(s,16);
  float m = s*(1.f/256.f);
  float vs=0.f;
  #pragma unroll
  for (int i=0;i<8;i++){ float d = v[i]-m; vs += d*d; }
  vs += __shfl_xor(vs,1); vs+=__shfl_xor(vs,2); vs+=__shfl_xor(vs,4);
  vs += __shfl_xor(vs,8); vs+=__shfl_xor(vs,16);
  float rstd = rsqrtf(vs*(1.f/256.f) + 1e-5f);
  float dp = 0.f;
  #pragma unroll
  for (int i=0;i<8;i++){
    int d = j*8+i;
    float snv = (v[i]-m)*rstd*g[d] + be[d];
    sn[r][d] = f2b(snv);
    dp += snv * wqbk[d];
  }
  dp += __shfl_xor(dp,1); dp+=__shfl_xor(dp,2); dp+=__shfl_xor(dp,4);
  dp += __shfl_xor(dp,8); dp+=__shfl_xor(dp,16);
  if (j==0) dotbias[b*16+r] = dp + cbk[0];
  for (int rr=8; rr<16; ++rr){ sn[rr][t]=0; if (t<8) sn[rr][256+t]=0; }
  __syncthreads();
  int lane = t&63, wv = t>>6, l16 = lane&15, quad = lane>>4;
  #pragma unroll
  for (int nt=0; nt<4; ++nt){
    int col = (wv*4+nt)*16 + l16;
    f32x4 acc = {0.f,0.f,0.f,0.f};
    #pragma unroll
    for (int kk=0;kk<8;kk++){
      int kd = kk*32 + quad*8;
      bf16x8 a = *(const bf16x8*)&sn[l16][kd];
      bf16x8 bb = *(const bf16x8*)(WcT + col*256 + kd);
      acc = mfma16(a,bb,acc);
    }
    float bcv = bc[col];
    #pragma unroll
    for (int ri=0;ri<4;ri++){
      int rw = quad*4+ri;
      qp[(b*16+rw)*256 + col] = f2b(acc[ri] + bcv);
    }
  }
}

// ---------- shared per-tile attention core (stage 2 + PT + PV) ----------
// Implemented inline in both iter kernels below.

// ---------- I2a (iteration 0): fused LN + dots + softmax + MFMA-PV ----------
// grid = 64 batches x 16 chunks = 1024 blocks, 4 tiles of 64 tokens each.
// PV: attn split hi/lo into PT rows 0-7 / 8-15; one MFMA set computes both;
// u = D[r] + shfl_xor(D[r],32).
__global__ __launch_bounds__(256) void k_iter0(
    const float* __restrict__ in, const float* __restrict__ g,
    const float* __restrict__ be, const unsigned short* __restrict__ qp,
    const float* __restrict__ dotbias, float* __restrict__ attn_sum,
    float* __restrict__ upart, unsigned short* __restrict__ xc_w){
  __shared__ __align__(16) unsigned short xt[XT_ELEMS];
  __shared__ __align__(16) unsigned short PTm[16][72];
  int t = threadIdx.x;
  int b = blockIdx.x >> 4, sp = blockIdx.x & 15;
  int lane=t&63, wv=t>>6, l16=lane&15, quad=lane>>4;
  bf16x8 aq[8];
  #pragma unroll
  for (int kk=0;kk<8;kk++)
    aq[kk] = *(const bf16x8*)(qp + ((size_t)(b*16+l16))*256 + kk*32+quad*8);
  float db[4];
  #pragma unroll
  for (int ri=0;ri<4;ri++) db[ri] = dotbias[b*16 + quad*4 + ri];
  f32x4 acc4[4];
  #pragma unroll
  for (int i=0;i<4;i++){ acc4[i][0]=0;acc4[i][1]=0;acc4[i][2]=0;acc4[i][3]=0; }
  float rbs[4] = {0.f,0.f,0.f,0.f};
  int rl2 = t>>4, j2 = t&15;
  for (int tile=0; tile<4; ++tile){
    int n0 = sp*256 + tile*64;
    __syncthreads();   // xt/PT free from previous tile's readers
    // --- stage 1: LN(inputs) -> subtiled LDS bf16 + linear global cache ---
    #pragma unroll
    for (int p=0;p<4;p++){
      int row = p*16 + rl2;
      const float* pr = in + ((size_t)(b*4096 + n0 + row))*256 + j2*16;
      float v[16]; float s=0.f;
      #pragma unroll
      for (int c=0;c<4;c++) *(float4*)(v+c*4) = *(const float4*)(pr + c*4);
      #pragma unroll
      for (int i=0;i<16;i++) s += v[i];
      s += __shfl_xor(s,1); s+=__shfl_xor(s,2); s+=__shfl_xor(s,4); s+=__shfl_xor(s,8);
      float m = s*(1.f/256.f);
      float vs=0.f;
      #pragma unroll
      for (int i=0;i<16;i++){ float d=v[i]-m; vs+=d*d; }
      vs+=__shfl_xor(vs,1); vs+=__shfl_xor(vs,2); vs+=__shfl_xor(vs,4); vs+=__shfl_xor(vs,8);
      float rstd = rsqrtf(vs*(1.f/256.f)+1e-5f);
      #pragma unroll
      for (int c=0;c<2;c++){
        float o[8];
        #pragma unroll
        for (int q=0;q<8;q++){
          int d = j2*16 + c*8 + q;
          o[q] = (v[c*8+q]-m)*rstd*g[d] + be[d];
        }
        uint4 w4;
        w4.x=pck(o[0],o[1]); w4.y=pck(o[2],o[3]);
        w4.z=pck(o[4],o[5]); w4.w=pck(o[6],o[7]);
        *(uint4*)&xt[xti(row, j2*16 + c*8)] = w4;
        *(uint4*)(xc_w + ((size_t)(b*4096 + n0 + row))*256 + j2*16 + c*8) = w4;
      }
    }
    __syncthreads();
    // --- stage 2: dots + softmax over slots ---
    f32x4 dacc = {0.f,0.f,0.f,0.f};
    #pragma unroll
    for (int kk=0;kk<8;kk++){
      bf16x8 bb = *(const bf16x8*)&xt[xti(wv*16 + l16, kk*32 + quad*8)];
      dacc = mfma16(aq[kk],bb,dacc);
    }
    const float scale = 0.0625f;
    float val[4];
    #pragma unroll
    for (int ri=0;ri<4;ri++) val[ri] = (dacc[ri] + db[ri]) * scale;
    float mx = fmaxf(fmaxf(val[0],val[1]), fmaxf(val[2],val[3]));
    mx = fmaxf(mx, __shfl_xor(mx,16));
    float e[4], s4=0.f;
    #pragma unroll
    for (int ri=0;ri<4;ri++){ e[ri] = expf(val[ri]-mx); s4 += e[ri]; }
    float s8 = s4 + __shfl_xor(s4,16);
    float inv = 1.f/s8;
    float av[4];
    #pragma unroll
    for (int ri=0;ri<4;ri++) av[ri] = e[ri]*inv;
    if (quad < 2){
      int nn = wv*16 + l16;
      #pragma unroll
      for (int ri=0;ri<4;ri++){
        unsigned short h = f2b(av[ri]);
        unsigned short lw = f2b(av[ri] - b2f(h));
        PTm[quad*4+ri][nn] = h;
        PTm[8+quad*4+ri][nn] = lw;
        float ss = av[ri];
        ss += __shfl_xor(ss,1); ss+=__shfl_xor(ss,2);
        ss += __shfl_xor(ss,4); ss+=__shfl_xor(ss,8);
        if (l16==0) rbs[ri] += ss;
      }
    }
    __syncthreads();
    // --- stage 3: u += attn(hi|lo) @ x via MFMA; B-frags via u16 gather ---
    bf16x8 pa0 = *(const bf16x8*)&PTm[l16][quad*8];
    bf16x8 pa1 = *(const bf16x8*)&PTm[l16][32 + quad*8];
    #pragma unroll
    for (int i=0;i<4;i++){
      int cOff = (wv*4+i)*72 + l16;
      #pragma unroll
      for (int kk2=0;kk2<2;kk2++){
        int base = (kk2*8 + quad*2)*1160 + cOff;
        unsigned short xv[8];
        #pragma unroll
        for (int j=0;j<8;j++)
          xv[j] = xt[base + (j&3)*16 + (j>>2)*1160];
        union { unsigned u[4]; bf16x8 v; } U;
        #pragma unroll
        for (int w2=0;w2<4;w2++)
          U.u[w2] = (unsigned)xv[2*w2] | ((unsigned)xv[2*w2+1]<<16);
        acc4[i] = mfma16(kk2 ? pa1 : pa0, U.v, acc4[i]);
      }
    }
  }
  // --- epilogue: u = hi + lo, write upart ---
  float* o = upart + (size_t)sp*131072 + ((size_t)b*8)*256;
  #pragma unroll
  for (int i=0;i<4;i++){
    #pragma unroll
    for (int ri=0;ri<4;ri++){
      float hiv = acc4[i][ri];
      float lov = __shfl_xor(hiv, 32);
      if (quad < 2)
        o[(quad*4+ri)*256 + (wv*4+i)*16 + l16] = hiv + lov;
    }
  }
  if (quad < 2 && l16 == 0){
    #pragma unroll
    for (int ri=0;ri<4;ri++)
      atomicAdd(&attn_sum[b*8 + quad*4 + ri], rbs[ri]);
  }
}

// ---------- I2b (iterations 1,2): bf16 cache -> subtiled LDS; MFMA-PV ----------
__global__ __launch_bounds__(256) void k_iter(
    const unsigned short* __restrict__ xc,
    const unsigned short* __restrict__ qp,
    const float* __restrict__ dotbias, float* __restrict__ attn_sum,
    float* __restrict__ upart, float* __restrict__ attn_out){
  __shared__ __align__(16) unsigned short xt[XT_ELEMS];
  __shared__ __align__(16) unsigned short PTm[16][72];
  int t = threadIdx.x;
  int b = blockIdx.x >> 4, sp = blockIdx.x & 15;
  int lane=t&63, wv=t>>6, l16=lane&15, quad=lane>>4;
  bf16x8 aq[8];
  #pragma unroll
  for (int kk=0;kk<8;kk++)
    aq[kk] = *(const bf16x8*)(qp + ((size_t)(b*16+l16))*256 + kk*32+quad*8);
  float db[4];
  #pragma unroll
  for (int ri=0;ri<4;ri++) db[ri] = dotbias[b*16 + quad*4 + ri];
  f32x4 acc4[4];
  #pragma unroll
  for (int i=0;i<4;i++){ acc4[i][0]=0;acc4[i][1]=0;acc4[i][2]=0;acc4[i][3]=0; }
  float rbs[4] = {0.f,0.f,0.f,0.f};
  int rl = t>>3, j = t&7;
  const unsigned short* cbase = xc + ((size_t)(b*4096 + sp*256))*256;
  for (int tile=0; tile<4; ++tile){
    __syncthreads();   // xt/PT free from previous tile's readers
    // --- stage 1: global bf16 cache -> subtiled LDS ---
    const unsigned short* tb = cbase + (size_t)tile*64*256;
    #pragma unroll
    for (int p=0;p<2;p++){
      int row = p*32 + rl;
      const unsigned short* pr = tb + (size_t)row*256 + j*32;
      #pragma unroll
      for (int c=0;c<4;c++){
        uint4 w4 = *(const uint4*)(pr + c*8);
        *(uint4*)&xt[xti(row, j*32 + c*8)] = w4;
      }
    }
    __syncthreads();
    // --- stage 2: dots + softmax ---
    f32x4 dacc = {0.f,0.f,0.f,0.f};
    #pragma unroll
    for (int kk=0;kk<8;kk++){
      bf16x8 bb = *(const bf16x8*)&xt[xti(wv*16 + l16, kk*32 + quad*8)];
      dacc = mfma16(aq[kk],bb,dacc);
    }
    const float scale = 0.0625f;
    float val[4];
    #pragma unroll
    for (int ri=0;ri<4;ri++) val[ri] = (dacc[ri] + db[ri]) * scale;
    float mx = fmaxf(fmaxf(val[0],val[1]), fmaxf(val[2],val[3]));
    mx = fmaxf(mx, __shfl_xor(mx,16));
    float e[4], s4=0.f;
    #pragma unroll
    for (int ri=0;ri<4;ri++){ e[ri] = expf(val[ri]-mx); s4 += e[ri]; }
    float s8 = s4 + __shfl_xor(s4,16);
    float inv = 1.f/s8;
    float av[4];
    #pragma unroll
    for (int ri=0;ri<4;ri++) av[ri] = e[ri]*inv;
    int n0 = sp*256 + tile*64;
    if (quad < 2){
      int nn = wv*16 + l16;
      #pragma unroll
      for (int ri=0;ri<4;ri++){
        int kr = quad*4+ri;
        unsigned short h = f2b(av[ri]);
        unsigned short lw = f2b(av[ri] - b2f(h));
        PTm[kr][nn] = h;
        PTm[8+kr][nn] = lw;
        if (attn_out)
          attn_out[((size_t)(b*8+kr))*4096 + n0 + nn] = av[ri];
        float ss = av[ri];
        ss += __shfl_xor(ss,1); ss+=__shfl_xor(ss,2);
        ss += __shfl_xor(ss,4); ss+=__shfl_xor(ss,8);
        if (l16==0) rbs[ri] += ss;
      }
    }
    __syncthreads();
    // --- stage 3: u += attn(hi|lo) @ x via MFMA; B-frags via u16 gather ---
    bf16x8 pa0 = *(const bf16x8*)&PTm[l16][quad*8];
    bf16x8 pa1 = *(const bf16x8*)&PTm[l16][32 + quad*8];
    #pragma unroll
    for (int i=0;i<4;i++){
      int cOff = (wv*4+i)*72 + l16;
      #pragma unroll
      for (int kk2=0;kk2<2;kk2++){
        int base = (kk2*8 + quad*2)*1160 + cOff;
        unsigned short xv[8];
        #pragma unroll
        for (int jj=0;jj<8;jj++)
          xv[jj] = xt[base + (jj&3)*16 + (jj>>2)*1160];
        union { unsigned u[4]; bf16x8 v; } U;
        #pragma unroll
        for (int w2=0;w2<4;w2++)
          U.u[w2] = (unsigned)xv[2*w2] | ((unsigned)xv[2*w2+1]<<16);
        acc4[i] = mfma16(kk2 ? pa1 : pa0, U.v, acc4[i]);
      }
    }
  }
  // --- epilogue: u = hi + lo, write upart ---
  float* o = upart + (size_t)sp*131072 + ((size_t)b*8)*256;
  #pragma unroll
  for (int i=0;i<4;i++){
    #pragma unroll
    for (int ri=0;ri<4;ri++){
      float hiv = acc4[i][ri];
      float lov = __shfl_xor(hiv, 32);
      if (quad < 2)
        o[(quad*4+ri)*256 + (wv*4+i)*16 + l16] = hiv + lov;
    }
  }
  if (quad < 2 && l16 == 0){
    #pragma unroll
    for (int ri=0;ri<4;ri++)
      atomicAdd(&attn_sum[b*8 + quad*4 + ri], rbs[ri]);
  }
}

// ---------- I3 fused slot chain (round-2 known-good 512-thread version) ----------
__global__ __launch_bounds__(512) void k_step(
    const float* __restrict__ upart, float* __restrict__ asum,
    float* __restrict__ sf, unsigned short* __restrict__ sb,
    const unsigned short* __restrict__ WvihT, const float* __restrict__ bvih,
    const unsigned short* __restrict__ Whhb, const float* __restrict__ bhh,
    const float* __restrict__ lnffg, const float* __restrict__ lnffb,
    const unsigned short* __restrict__ W1b, const float* __restrict__ b1,
    const unsigned short* __restrict__ W2b, const float* __restrict__ b2v,
    const float* __restrict__ lnsg, const float* __restrict__ lnsb,
    const unsigned short* __restrict__ WcT, const float* __restrict__ bc,
    const float* __restrict__ wqbk, const float* __restrict__ cbk,
    unsigned short* __restrict__ qp, float* __restrict__ dotb,
    float* __restrict__ out_slots, int last){
  __shared__ __align__(16) unsigned short ub16[16][264];
  __shared__ __align__(16) float hls[16][268];
  __shared__ __align__(16) unsigned short sn[16][264];
  __shared__ __align__(16) unsigned short s1t[16][520];
  __shared__ float redh[8][16], redq[8][16], mr[16], rs[16];
  int t = threadIdx.x;
  int Bk = blockIdx.x;                 // batches 2*Bk, 2*Bk+1
  int bb0 = Bk*2;
  int lane=t&63, wv=t>>6, l16=lane&15, quad=lane>>4;
  {
    int r16 = t>>5, c0 = (t&31)*8;
    size_t base = ((size_t)(Bk*16 + r16))*256 + c0;
    float4 a0={0,0,0,0}, a1={0,0,0,0};
    #pragma unroll
    for (int sp2=0; sp2<16; ++sp2){
      const float* p = upart + (size_t)sp2*131072 + base;
      float4 u0=*(const float4*)(p+0), u1=*(const float4*)(p+4);
      a0.x+=u0.x;a0.y+=u0.y;a0.z+=u0.z;a0.w+=u0.w;
      a1.x+=u1.x;a1.y+=u1.y;a1.z+=u1.z;a1.w+=u1.w;
    }
    float inv = 1.f/(asum[Bk*16 + r16] + 1e-8f);
    float uu[8] = {a0.x,a0.y,a0.z,a0.w,a1.x,a1.y,a1.z,a1.w};
    #pragma unroll
    for (int c=0;c<8;c+=2)
      *(unsigned int*)&ub16[r16][c0+c] = pck(uu[c]*inv, uu[c+1]*inv);
  }
  __syncthreads();
  if (t < 16) asum[Bk*16 + t] = 0.f;
  bf16x8 afi[8], afh[8];
  #pragma unroll
  for (int kk=0;kk<8;kk++){
    int kd = kk*32+quad*8;
    afi[kk] = *(const bf16x8*)&ub16[l16][kd];
    afh[kk] = *(const bf16x8*)(sb + ((size_t)(Bk*16+l16))*256 + kd);
  }
  float sh[4]={0,0,0,0}, sq[4]={0,0,0,0};
  #pragma unroll
  for (int jj=0;jj<2;jj++){
    int jt = wv*2 + jj;
    int dR = jt*16 + l16;
    f32x4 cIR={0,0,0,0}, cIZ={0,0,0,0}, cIN={0,0,0,0};
    f32x4 cHR={0,0,0,0}, cHZ={0,0,0,0}, cHN={0,0,0,0};
    #pragma unroll
    for (int kk=0;kk<8;kk++){
      int kd = kk*32+quad*8;
      cIR = mfma16(afi[kk], *(const bf16x8*)(WvihT + (size_t)dR*256 + kd), cIR);
      cIZ = mfma16(afi[kk], *(const bf16x8*)(WvihT + (size_t)(256+dR)*256 + kd), cIZ);
      cIN = mfma16(afi[kk], *(const bf16x8*)(WvihT + (size_t)(512+dR)*256 + kd), cIN);
      cHR = mfma16(afh[kk], *(const bf16x8*)(Whhb + (size_t)dR*256 + kd), cHR);
      cHZ = mfma16(afh[kk], *(const bf16x8*)(Whhb + (size_t)(256+dR)*256 + kd), cHZ);
      cHN = mfma16(afh[kk], *(const bf16x8*)(Whhb + (size_t)(512+dR)*256 + kd), cHN);
    }
    float biR = bvih[dR], biZ = bvih[256+dR], biN = bvih[512+dR];
    float bhR = bhh[dR], bhZ = bhh[256+dR], bhN = bhh[512+dR];
    #pragma unroll
    for (int ri=0;ri<4;ri++){
      int row = quad*4+ri;
      float hp = sf[((size_t)(Bk*16+row))*256 + dR];
      float rg = sigm(cIR[ri]+biR + cHR[ri]+bhR);
      float z  = sigm(cIZ[ri]+biZ + cHZ[ri]+bhZ);
      float nn = tanhf(cIN[ri]+biN + rg*(cHN[ri]+bhN));
      float h = (1.f-z)*nn + z*hp;
      hls[row][dR] = h;
      sh[ri] += h; sq[ri] += h*h;
    }
  }
  #pragma unroll
  for (int ri=0;ri<4;ri++){
    sh[ri]+=__shfl_xor(sh[ri],1); sh[ri]+=__shfl_xor(sh[ri],2);
    sh[ri]+=__shfl_xor(sh[ri],4); sh[ri]+=__shfl_xor(sh[ri],8);
    sq[ri]+=__shfl_xor(sq[ri],1); sq[ri]+=__shfl_xor(sq[ri],2);
    sq[ri]+=__shfl_xor(sq[ri],4); sq[ri]+=__shfl_xor(sq[ri],8);
  }
  if (l16==0){
    #pragma unroll
    for (int ri=0;ri<4;ri++){
      redh[wv][quad*4+ri] = sh[ri];
      redq[wv][quad*4+ri] = sq[ri];
    }
  }
  __syncthreads();
  if (t < 16){
    float s = redh[0][t]+redh[1][t]+redh[2][t]+redh[3][t]
            + redh[4][t]+redh[5][t]+redh[6][t]+redh[7][t];
    float q = redq[0][t]+redq[1][t]+redq[2][t]+redq[3][t]
            + redq[4][t]+redq[5][t]+redq[6][t]+redq[7][t];
    float m = s*(1.f/256.f);
    float var = q*(1.f/256.f) - m*m;
    mr[t] = m; rs[t] = rsqrtf(var + 1e-5f);
  }
  __syncthreads();
  {
    int row = t>>5, c0 = (t&31)*8;
    float m = mr[row], rstd = rs[row];
    #pragma unroll
    for (int c=0;c<8;c+=2){
      int d = c0+c;
      float o0 = (hls[row][d]-m)*rstd*lnffg[d] + lnffb[d];
      float o1 = (hls[row][d+1]-m)*rstd*lnffg[d+1] + lnffb[d+1];
      *(unsigned int*)&sn[row][d] = pck(o0,o1);
    }
  }
  __syncthreads();
  {
    bf16x8 af[8];
    #pragma unroll
    for (int kk=0;kk<8;kk++)
      af[kk] = *(const bf16x8*)&sn[l16][kk*32+quad*8];
    #pragma unroll
    for (int ct=wv*4; ct<wv*4+4; ++ct){
      int col = ct*16+l16;
      f32x4 acc={0,0,0,0};
      #pragma unroll
      for (int kk=0;kk<8;kk++)
        acc = mfma16(af[kk], *(const bf16x8*)(W1b + (size_t)col*256 + kk*32+quad*8), acc);
      float bb = b1[col];
      #pragma unroll
      for (int ri=0;ri<4;ri++){
        float v2 = acc[ri]+bb; v2 = v2>0.f? v2:0.f;
        s1t[quad*4+ri][col] = f2b(v2);
      }
    }
  }
  __syncthreads();
  {
    bf16x8 af[16];
    #pragma unroll
    for (int kk=0;kk<16;kk++)
      af[kk] = *(const bf16x8*)&s1t[l16][kk*32+quad*8];
    #pragma unroll
    for (int ct=wv*2; ct<wv*2+2; ++ct){
      int col = ct*16+l16;
      f32x4 acc={0,0,0,0};
      #pragma unroll
      for (int kk=0;kk<16;kk++)
        acc = mfma16(af[kk], *(const bf16x8*)(W2b + (size_t)col*512 + kk*32+quad*8), acc);
      float bb = b2v[col];
      #pragma unroll
      for (int ri=0;ri<4;ri++){
        int row = quad*4+ri;
        float v2 = acc[ri] + bb + hls[row][col];
        size_t gidx = ((size_t)(Bk*16+row))*256 + col;
        sf[gidx] = v2;
        sb[gidx] = f2b(v2);
        if (last) out_slots[gidx] = v2;
        hls[row][col] = v2;
      }
    }
  }
  if (!last){
    __syncthreads();
    {
      int row = t>>5, c0 = (t&31)*8;
      float ps=0.f, pq=0.f;
      float hv[8];
      #pragma unroll
      for (int c=0;c<8;c++){ hv[c]=hls[row][c0+c]; ps+=hv[c]; pq+=hv[c]*hv[c]; }
      ps+=__shfl_xor(ps,1); ps+=__shfl_xor(ps,2); ps+=__shfl_xor(ps,4);
      ps+=__shfl_xor(ps,8); ps+=__shfl_xor(ps,16);
      pq+=__shfl_xor(pq,1); pq+=__shfl_xor(pq,2); pq+=__shfl_xor(pq,4);
      pq+=__shfl_xor(pq,8); pq+=__shfl_xor(pq,16);
      float m = ps*(1.f/256.f);
      float var = pq*(1.f/256.f) - m*m;
      float rstd = rsqrtf(var + 1e-5f);
      float dp = 0.f;
      #pragma unroll
      for (int c=0;c<8;c+=2){
        int d = c0+c;
        float o0 = (hv[c]-m)*rstd*lnsg[d] + lnsb[d];
        float o1 = (hv[c+1]-m)*rstd*lnsg[d+1] + lnsb[d+1];
        dp += o0*wqbk[d] + o1*wqbk[d+1];
        *(unsigned int*)&sn[row][d] = pck(o0,o1);
      }
      dp+=__shfl_xor(dp,1); dp+=__shfl_xor(dp,2); dp+=__shfl_xor(dp,4);
      dp+=__shfl_xor(dp,8); dp+=__shfl_xor(dp,16);
      if ((t&31)==0){
        int bloc = row>>3, rr = row&7;
        dotb[(bb0+bloc)*16 + rr] = dp + cbk[0];
      }
    }
    __syncthreads();
    {
      bf16x8 af[8];
      #pragma unroll
      for (int kk=0;kk<8;kk++)
        af[kk] = *(const bf16x8*)&sn[l16][kk*32+quad*8];
      #pragma unroll
      for (int ct=wv*2; ct<wv*2+2; ++ct){
        int col = ct*16+l16;
        f32x4 acc={0,0,0,0};
        #pragma unroll
        for (int kk=0;kk<8;kk++)
          acc = mfma16(af[kk], *(const bf16x8*)(WcT + (size_t)col*256 + kk*32+quad*8), acc);
        float bcv = bc[col];
        #pragma unroll
        for (int ri=0;ri<4;ri++){
          int row = quad*4+ri;
          int bloc = row>>3, rr = row&7;
          qp[((size_t)((bb0+bloc)*16 + rr))*256 + col] = f2b(acc[ri] + bcv);
        }
      }
    }
  }
}

// ---------- launch ----------
extern "C" void kernel_launch(void* const* d_in, const int* in_sizes, int n_in,
                              void* d_out, int out_size, void* d_ws, size_t ws_size,
                              hipStream_t stream){
  const float* inputs  = (const float*)d_in[0];
  const float* noise   = (const float*)d_in[1];
  const float* slot_mu = (const float*)d_in[2];
  const float* slot_ls = (const float*)d_in[3];
  const float* Wq   = (const float*)d_in[4];
  const float* bq   = (const float*)d_in[5];
  const float* Wk   = (const float*)d_in[6];
  const float* bk   = (const float*)d_in[7];
  const float* Wv   = (const float*)d_in[8];
  const float* bv   = (const float*)d_in[9];
  const float* W_ih = (const float*)d_in[10];
  const float* b_ih = (const float*)d_in[11];
  const float* W_hh = (const float*)d_in[12];
  const float* b_hh = (const float*)d_in[13];
  const float* ln_in_g = (const float*)d_in[14];
  const float* ln_in_b = (const float*)d_in[15];
  const float* ln_s_g  = (const float*)d_in[16];
  const float* ln_s_b  = (const float*)d_in[17];
  const float* ln_ff_g = (const float*)d_in[18];
  const float* ln_ff_b = (const float*)d_in[19];
  const float* W1 = (const float*)d_in[20];
  const float* b1 = (const float*)d_in[21];
  const float* W2 = (const float*)d_in[22];
  const float* b2 = (const float*)d_in[23];

  char* w = (char*)d_ws;
  auto alloc = [&](size_t n)->char*{ char* p=w; w += (n+255)&~(size_t)255; return p; };
  unsigned short* xc   = (unsigned short*)alloc(134217728);  // [B*N,256] bf16 LN'd cache
  float* upart         = (float*)alloc(8388608);             // [16,B,8,256] f32
  unsigned short* qp   = (unsigned short*)alloc(524288);     // [B,16,256] bf16
  float* sf            = (float*)alloc(524288);              // slots f32
  unsigned short* sb   = (unsigned short*)alloc(262144);     // slots bf16
  unsigned short* WcT  = (unsigned short*)alloc(131072);     // [256,256] bf16
  unsigned short* WvihT= (unsigned short*)alloc(393216);     // [768,256] bf16
  unsigned short* Whhb = (unsigned short*)alloc(393216);     // [768,256] bf16
  unsigned short* W1b  = (unsigned short*)alloc(262144);     // [512,256] bf16
  unsigned short* W2b  = (unsigned short*)alloc(262144);     // [256,512] bf16
  float* bc    = (float*)alloc(1024);
  float* wqbk  = (float*)alloc(1024);
  float* cbk   = (float*)alloc(256);
  float* bvih  = (float*)alloc(3072);
  float* dotb  = (float*)alloc(4096);
  float* asum  = (float*)alloc(2048);

  float* out_slots = (float*)d_out;
  float* out_attn  = out_slots + 131072;

  k_slots_init<<<dim3(512),dim3(256),0,stream>>>(noise, slot_mu, slot_ls, sf, sb);
  k_pre1<<<dim3(256),dim3(256),0,stream>>>(Wq, Wk, bq, bk, WcT, bc, wqbk, cbk);
  k_pre2<<<dim3(768),dim3(256),0,stream>>>(W_ih, Wv, bv, b_ih, WvihT, bvih);
  k_prep_b16<<<dim3(1792),dim3(256),0,stream>>>(W_hh, W1, W2, Whhb, W1b, W2b);
  k_slot_q<<<dim3(64),dim3(256),0,stream>>>(sf, ln_s_g, ln_s_b, WcT, bc, wqbk, cbk,
                                            qp, dotb, asum);

  for (int it=0; it<3; ++it){
    int last = (it==2);
    if (it==0){
      k_iter0<<<dim3(1024),dim3(256),0,stream>>>(
          inputs, ln_in_g, ln_in_b, qp, dotb, asum, upart, xc);
    } else {
      k_iter<<<dim3(1024),dim3(256),0,stream>>>(
          xc, qp, dotb, asum, upart,
          last ? out_attn : (float*)nullptr);
    }
    k_step<<<dim3(32),dim3(512),0,stream>>>(
        upart, asum, sf, sb, WvihT, bvih, Whhb, b_hh,
        ln_ff_g, ln_ff_b, W1b, b1, W2b, b2,
        ln_s_g, ln_s_b, WcT, bc, wqbk, cbk,
        qp, dotb, last ? out_slots : (float*)nullptr, last);
  }
}